// Round 1
// baseline (3325.653 us; speedup 1.0000x reference)
//
#include <hip/hip_runtime.h>

// GraphEncoder: MHA + 3×(GAT + residual-proj + LN[+ELU]), fp32 baseline.
// B=64, N=400, D=400, Hd=256, E=128, H=4, hd=64.
// d_out layout (f32): x_final [64*400*128] | attn1 [64*400*400] | attn2 | attn3

#define NEGBIG (-1e9f)

constexpr int BM = 64, BN = 64, BK = 16;

__device__ inline float wave_max(float v) {
#pragma unroll
    for (int off = 32; off >= 1; off >>= 1)
        v = fmaxf(v, __shfl_xor(v, off, 64));
    return v;
}
__device__ inline float wave_sum(float v) {
#pragma unroll
    for (int off = 32; off >= 1; off >>= 1)
        v += __shfl_xor(v, off, 64);
    return v;
}

// C[M,Nc] = A[M,K] @ W[K,Nc] (+bias) (+resid) (+=C). Batched via blockIdx.z.
// Requires K % BK == 0 (holds: 400/256/128). M,Nc guarded.
template<bool BIAS, bool ACCUM, bool RESID>
__global__ __launch_bounds__(256) void gemm_f32(
    const float* __restrict__ A, const float* __restrict__ W,
    const float* __restrict__ bias, const float* __restrict__ resid,
    float* __restrict__ C, int M, int K, int Nc,
    long sA, long sW, long sC)
{
    const int bz = blockIdx.z;
    A += (long)bz * sA;
    W += (long)bz * sW;
    C += (long)bz * sC;
    const float* R = RESID ? (resid + (long)bz * sC) : nullptr;

    __shared__ float As[BK][BM + 4];
    __shared__ float Bs[BK][BN + 4];

    const int tid = threadIdx.x;
    const int tx = tid & 15;        // 0..15 (col group)
    const int ty = tid >> 4;        // 0..15 (row group)
    const int m0 = blockIdx.y * BM;
    const int n0 = blockIdx.x * BN;

    // A-load indices: 16 k's x 16 rows per pass, 4 passes
    const int la_k = tid & 15;
    const int la_m = tid >> 4;
    // B-load indices: 64 cols x 4 k's per pass, 4 passes
    const int lb_n = tid & 63;
    const int lb_k = tid >> 6;

    float acc[4][4] = {};

    for (int k0 = 0; k0 < K; k0 += BK) {
#pragma unroll
        for (int r = 0; r < 4; ++r) {
            const int m = la_m + 16 * r;
            const int gm = m0 + m;
            As[la_k][m] = (gm < M) ? A[(long)gm * K + (k0 + la_k)] : 0.f;
        }
#pragma unroll
        for (int r = 0; r < 4; ++r) {
            const int k = lb_k + 4 * r;
            const int gn = n0 + lb_n;
            Bs[k][lb_n] = (gn < Nc) ? W[(long)(k0 + k) * Nc + gn] : 0.f;
        }
        __syncthreads();
#pragma unroll
        for (int k = 0; k < BK; ++k) {
            const float4 av = *reinterpret_cast<const float4*>(&As[k][ty * 4]);
            const float4 bv = *reinterpret_cast<const float4*>(&Bs[k][tx * 4]);
            const float a4[4] = {av.x, av.y, av.z, av.w};
            const float b4[4] = {bv.x, bv.y, bv.z, bv.w};
#pragma unroll
            for (int i = 0; i < 4; ++i)
#pragma unroll
                for (int j = 0; j < 4; ++j)
                    acc[i][j] += a4[i] * b4[j];
        }
        __syncthreads();
    }

#pragma unroll
    for (int i = 0; i < 4; ++i) {
        const int gm = m0 + ty * 4 + i;
        if (gm < M) {
#pragma unroll
            for (int j = 0; j < 4; ++j) {
                const int gn = n0 + tx * 4 + j;
                if (gn < Nc) {
                    float v = acc[i][j];
                    if (BIAS) v += bias[gn];
                    if (RESID) v += R[(long)gm * Nc + gn];
                    if (ACCUM) v += C[(long)gm * Nc + gn];
                    C[(long)gm * Nc + gn] = v;
                }
            }
        }
    }
}

// Fused MHA attention: one block per (b,i), wave w = head w.
// scores = q.k/8, mask, softmax, ctx = attn @ v. q,k,v: [B*N, 256] (head h at cols h*64..h*64+63)
__global__ __launch_bounds__(256) void mha_attn_kernel(
    const float* __restrict__ q, const float* __restrict__ k,
    const float* __restrict__ v, const float* __restrict__ adj,
    float* __restrict__ ctx)
{
    const int bi = blockIdx.x;          // b*400 + i
    const int b = bi / 400;
    const int tid = threadIdx.x;
    const int wave = tid >> 6, lane = tid & 63;

    __shared__ float qsh[4][64];
    __shared__ float psh[4][400];

    qsh[wave][lane] = q[(long)bi * 256 + wave * 64 + lane];
    __syncthreads();

    const float* kb = k + (long)b * 400 * 256 + wave * 64;
    const float* adjrow = adj + (long)bi * 400;

    float s[7];
    float mx = -3.0e38f;
#pragma unroll
    for (int t = 0; t < 7; ++t) {
        const int j = lane + 64 * t;
        float dot = -3.0e38f;
        if (j < 400) {
            const float* krow = kb + (long)j * 256;
            float d0 = 0.f;
#pragma unroll
            for (int d = 0; d < 64; d += 4) {
                const float4 kv = *reinterpret_cast<const float4*>(krow + d);
                const float4 qv = *reinterpret_cast<const float4*>(&qsh[wave][d]);
                d0 += qv.x * kv.x + qv.y * kv.y + qv.z * kv.z + qv.w * kv.w;
            }
            d0 *= 0.125f;
            if (!(adjrow[j] > 0.f)) d0 = NEGBIG;
            dot = d0;
        }
        s[t] = dot;
        mx = fmaxf(mx, dot);
    }
    mx = wave_max(mx);

    float sum = 0.f;
#pragma unroll
    for (int t = 0; t < 7; ++t) {
        const int j = lane + 64 * t;
        if (j < 400) {
            const float p = expf(s[t] - mx);
            psh[wave][j] = p;
            sum += p;
        }
    }
    sum = wave_sum(sum);
    const float inv = 1.f / sum;
    __syncthreads();

    const float* vb = v + (long)b * 400 * 256 + wave * 64 + lane;
    float out = 0.f;
    for (int j = 0; j < 400; ++j)
        out += psh[wave][j] * vb[(long)j * 256];

    ctx[(long)bi * 256 + wave * 64 + lane] = out * inv;
}

// src[r] = h[r,:F].a[:F]; dst[r] = h[r,:F].a[F:2F]. One wave per row.
__global__ __launch_bounds__(256) void gat_srcdst(
    const float* __restrict__ h, const float* __restrict__ a,
    float* __restrict__ src, float* __restrict__ dst, int F)
{
    const int row = blockIdx.x * 4 + (threadIdx.x >> 6);
    const int lane = threadIdx.x & 63;
    const float* hp = h + (long)row * F;
    float s = 0.f, d = 0.f;
    for (int f = lane; f < F; f += 64) {
        const float hv = hp[f];
        s += hv * a[f];
        d += hv * a[F + f];
    }
    s = wave_sum(s);
    d = wave_sum(d);
    if (lane == 0) { src[row] = s; dst[row] = d; }
}

// attn[row, :] = softmax_j(mask(leaky_relu(src_i + dst_j, 0.2))). One wave per row.
__global__ __launch_bounds__(256) void gat_attn(
    const float* __restrict__ src, const float* __restrict__ dst,
    const float* __restrict__ adj, float* __restrict__ attn)
{
    const int row = blockIdx.x * 4 + (threadIdx.x >> 6);   // b*400+i
    const int b = row / 400;
    const int lane = threadIdx.x & 63;
    const float si = src[row];
    const float* db = dst + (long)b * 400;
    const float* adjrow = adj + (long)row * 400;

    float e[7];
    float mx = -3.0e38f;
#pragma unroll
    for (int t = 0; t < 7; ++t) {
        const int j = lane + 64 * t;
        float v = -3.0e38f;
        if (j < 400) {
            v = si + db[j];
            v = (v > 0.f) ? v : 0.2f * v;
            if (!(adjrow[j] > 0.f)) v = NEGBIG;
        }
        e[t] = v;
        mx = fmaxf(mx, v);
    }
    mx = wave_max(mx);

    float p[7];
    float sum = 0.f;
#pragma unroll
    for (int t = 0; t < 7; ++t) {
        const int j = lane + 64 * t;
        if (j < 400) {
            p[t] = expf(e[t] - mx);
            sum += p[t];
        }
    }
    sum = wave_sum(sum);
    const float inv = 1.f / sum;
#pragma unroll
    for (int t = 0; t < 7; ++t) {
        const int j = lane + 64 * t;
        if (j < 400) attn[(long)row * 400 + j] = p[t] * inv;
    }
}

// LayerNorm over last dim F (+optional ELU). One wave per row.
template<int F, bool ELU>
__global__ __launch_bounds__(256) void ln_kernel(
    const float* __restrict__ in, const float* __restrict__ g,
    const float* __restrict__ b, float* __restrict__ out)
{
    const int row = blockIdx.x * 4 + (threadIdx.x >> 6);
    const int lane = threadIdx.x & 63;
    constexpr int PER = F / 64;
    const float* ip = in + (long)row * F;

    float v[PER];
    float s = 0.f;
#pragma unroll
    for (int t = 0; t < PER; ++t) {
        v[t] = ip[lane + 64 * t];
        s += v[t];
    }
    s = wave_sum(s);
    const float mean = s * (1.f / F);
    float vs = 0.f;
#pragma unroll
    for (int t = 0; t < PER; ++t) {
        const float d = v[t] - mean;
        vs += d * d;
    }
    vs = wave_sum(vs);
    const float rstd = rsqrtf(vs * (1.f / F) + 1e-5f);
#pragma unroll
    for (int t = 0; t < PER; ++t) {
        const int col = lane + 64 * t;
        float y = (v[t] - mean) * rstd * g[col] + b[col];
        if (ELU) y = (y > 0.f) ? y : expm1f(y);
        out[(long)row * F + col] = y;
    }
}

extern "C" void kernel_launch(void* const* d_in, const int* in_sizes, int n_in,
                              void* d_out, int out_size, void* d_ws, size_t ws_size,
                              hipStream_t stream) {
    const float* x    = (const float*)d_in[0];
    const float* adj  = (const float*)d_in[1];
    const float* Wq   = (const float*)d_in[2];
    const float* bq   = (const float*)d_in[3];
    const float* Wk   = (const float*)d_in[4];
    const float* bk   = (const float*)d_in[5];
    const float* Wv   = (const float*)d_in[6];
    const float* bv   = (const float*)d_in[7];
    const float* Wo   = (const float*)d_in[8];
    const float* bo   = (const float*)d_in[9];
    const float* g1W  = (const float*)d_in[10];
    const float* g1a  = (const float*)d_in[11];
    const float* g2W  = (const float*)d_in[12];
    const float* g2a  = (const float*)d_in[13];
    const float* g3W  = (const float*)d_in[14];
    const float* g3a  = (const float*)d_in[15];
    const float* r1W  = (const float*)d_in[16];
    const float* r1b  = (const float*)d_in[17];
    const float* r2W  = (const float*)d_in[18];
    const float* r2b  = (const float*)d_in[19];
    const float* r3W  = (const float*)d_in[20];
    const float* r3b  = (const float*)d_in[21];
    const float* ln1g = (const float*)d_in[22];
    const float* ln1b = (const float*)d_in[23];
    const float* ln2g = (const float*)d_in[24];
    const float* ln2b = (const float*)d_in[25];
    const float* ln3g = (const float*)d_in[26];
    const float* ln3b = (const float*)d_in[27];

    float* out_x = (float*)d_out;              // [25600,128]
    float* attn1 = out_x + 3276800;            // [64,400,400]
    float* attn2 = attn1 + 10240000;
    float* attn3 = attn2 + 10240000;

    // workspace: 4 x [25600,256] f32 buffers + src/dst  (~105 MB)
    float* bufA = (float*)d_ws;                // q / h
    float* bufB = bufA + 6553600;              // k / res-accum
    float* bufC = bufB + 6553600;              // v / x3
    float* bufD = bufC + 6553600;              // ctx / x2
    float* srcb = bufD + 6553600;              // [25600]
    float* dstb = srcb + 25600;                // [25600]
    // xc (x after MHA residual, [25600,400]) lives in the attn1 output
    // region: it is dead before gat_attn writes attn1.
    float* xc = attn1;

    const dim3 blk(256);
    const int M = 25600;
    auto grid2 = [](int m, int n) { return dim3((unsigned)((n + BN - 1) / BN), (unsigned)((m + BM - 1) / BM), 1); };

    // ---- Phase 1: MHA ----
    gemm_f32<true, false, false><<<grid2(M, 256), blk, 0, stream>>>(x, Wq, bq, nullptr, bufA, M, 400, 256, 0, 0, 0);
    gemm_f32<true, false, false><<<grid2(M, 256), blk, 0, stream>>>(x, Wk, bk, nullptr, bufB, M, 400, 256, 0, 0, 0);
    gemm_f32<true, false, false><<<grid2(M, 256), blk, 0, stream>>>(x, Wv, bv, nullptr, bufC, M, 400, 256, 0, 0, 0);
    mha_attn_kernel<<<dim3(25600), blk, 0, stream>>>(bufA, bufB, bufC, adj, bufD);
    gemm_f32<true, false, true><<<grid2(M, 400), blk, 0, stream>>>(bufD, Wo, bo, x, xc, M, 256, 400, 0, 0, 0);

    // ---- Phase 2: GAT1 (Fin=400, F=256) ----
    gemm_f32<false, false, false><<<grid2(M, 256), blk, 0, stream>>>(xc, g1W, nullptr, nullptr, bufA, M, 400, 256, 0, 0, 0);
    gemm_f32<true, false, false><<<grid2(M, 256), blk, 0, stream>>>(xc, r1W, r1b, nullptr, bufB, M, 400, 256, 0, 0, 0);
    gat_srcdst<<<dim3(6400), blk, 0, stream>>>(bufA, g1a, srcb, dstb, 256);
    gat_attn<<<dim3(6400), blk, 0, stream>>>(srcb, dstb, adj, attn1);   // xc dead from here
    gemm_f32<false, true, false><<<dim3(4, 7, 64), blk, 0, stream>>>(attn1, bufA, nullptr, nullptr, bufB, 400, 400, 256, 160000, 102400, 102400);
    ln_kernel<256, true><<<dim3(6400), blk, 0, stream>>>(bufB, ln1g, ln1b, bufD);

    // ---- Phase 3: GAT2 (256 -> 256) ----
    gemm_f32<false, false, false><<<grid2(M, 256), blk, 0, stream>>>(bufD, g2W, nullptr, nullptr, bufA, M, 256, 256, 0, 0, 0);
    gemm_f32<true, false, false><<<grid2(M, 256), blk, 0, stream>>>(bufD, r2W, r2b, nullptr, bufB, M, 256, 256, 0, 0, 0);
    gat_srcdst<<<dim3(6400), blk, 0, stream>>>(bufA, g2a, srcb, dstb, 256);
    gat_attn<<<dim3(6400), blk, 0, stream>>>(srcb, dstb, adj, attn2);
    gemm_f32<false, true, false><<<dim3(4, 7, 64), blk, 0, stream>>>(attn2, bufA, nullptr, nullptr, bufB, 400, 400, 256, 160000, 102400, 102400);
    ln_kernel<256, true><<<dim3(6400), blk, 0, stream>>>(bufB, ln2g, ln2b, bufC);

    // ---- Phase 4: GAT3 (256 -> 128) ----
    gemm_f32<false, false, false><<<grid2(M, 128), blk, 0, stream>>>(bufC, g3W, nullptr, nullptr, bufA, M, 256, 128, 0, 0, 0);
    gemm_f32<true, false, false><<<grid2(M, 128), blk, 0, stream>>>(bufC, r3W, r3b, nullptr, bufB, M, 256, 128, 0, 0, 0);
    gat_srcdst<<<dim3(6400), blk, 0, stream>>>(bufA, g3a, srcb, dstb, 128);
    gat_attn<<<dim3(6400), blk, 0, stream>>>(srcb, dstb, adj, attn3);
    gemm_f32<false, true, false><<<dim3(2, 7, 64), blk, 0, stream>>>(attn3, bufA, nullptr, nullptr, bufB, 400, 400, 128, 160000, 51200, 51200);
    ln_kernel<128, false><<<dim3(6400), blk, 0, stream>>>(bufB, ln3g, ln3b, out_x);
}

// Round 3
// 1657.441 us; speedup vs baseline: 2.0065x; 2.0065x over previous
//
#include <hip/hip_runtime.h>

// GraphEncoder: MHA + 3×(GAT + residual-proj + LN[+ELU]), fp32.
// B=64, N=400, D=400, Hd=256, E=128, H=4, hd=64.
// d_out layout (f32): x_final [64*400*128] | attn1 [64*400*400] | attn2 | attn3

#define NEGBIG (-1e9f)

constexpr int BM = 64, BN = 64, BK = 16;

__device__ inline float wave_max(float v) {
#pragma unroll
    for (int off = 32; off >= 1; off >>= 1)
        v = fmaxf(v, __shfl_xor(v, off, 64));
    return v;
}
__device__ inline float wave_sum(float v) {
#pragma unroll
    for (int off = 32; off >= 1; off >>= 1)
        v += __shfl_xor(v, off, 64);
    return v;
}

// C[M,Nc] = A[M,K] @ W[K,Nc] (+bias) (+resid) (+=C). Batched via blockIdx.z.
// Requires K % BK == 0 (holds: 400/256/128). M,Nc guarded.
template<bool BIAS, bool ACCUM, bool RESID>
__global__ __launch_bounds__(256) void gemm_f32(
    const float* __restrict__ A, const float* __restrict__ W,
    const float* __restrict__ bias, const float* __restrict__ resid,
    float* __restrict__ C, int M, int K, int Nc,
    long sA, long sW, long sC)
{
    const int bz = blockIdx.z;
    A += (long)bz * sA;
    W += (long)bz * sW;
    C += (long)bz * sC;
    const float* R = RESID ? (resid + (long)bz * sC) : nullptr;

    __shared__ float As[BK][BM + 4];
    __shared__ float Bs[BK][BN + 4];

    const int tid = threadIdx.x;
    const int tx = tid & 15;        // 0..15 (col group)
    const int ty = tid >> 4;        // 0..15 (row group)
    const int m0 = blockIdx.y * BM;
    const int n0 = blockIdx.x * BN;

    const int la_k = tid & 15;
    const int la_m = tid >> 4;
    const int lb_n = tid & 63;
    const int lb_k = tid >> 6;

    float acc[4][4] = {};

    for (int k0 = 0; k0 < K; k0 += BK) {
#pragma unroll
        for (int r = 0; r < 4; ++r) {
            const int m = la_m + 16 * r;
            const int gm = m0 + m;
            As[la_k][m] = (gm < M) ? A[(long)gm * K + (k0 + la_k)] : 0.f;
        }
#pragma unroll
        for (int r = 0; r < 4; ++r) {
            const int k = lb_k + 4 * r;
            const int gn = n0 + lb_n;
            Bs[k][lb_n] = (gn < Nc) ? W[(long)(k0 + k) * Nc + gn] : 0.f;
        }
        __syncthreads();
#pragma unroll
        for (int k = 0; k < BK; ++k) {
            const float4 av = *reinterpret_cast<const float4*>(&As[k][ty * 4]);
            const float4 bv = *reinterpret_cast<const float4*>(&Bs[k][tx * 4]);
            const float a4[4] = {av.x, av.y, av.z, av.w};
            const float b4[4] = {bv.x, bv.y, bv.z, bv.w};
#pragma unroll
            for (int i = 0; i < 4; ++i)
#pragma unroll
                for (int j = 0; j < 4; ++j)
                    acc[i][j] += a4[i] * b4[j];
        }
        __syncthreads();
    }

#pragma unroll
    for (int i = 0; i < 4; ++i) {
        const int gm = m0 + ty * 4 + i;
        if (gm < M) {
#pragma unroll
            for (int j = 0; j < 4; ++j) {
                const int gn = n0 + tx * 4 + j;
                if (gn < Nc) {
                    float v = acc[i][j];
                    if (BIAS) v += bias[gn];
                    if (RESID) v += R[(long)gm * Nc + gn];
                    if (ACCUM) v += C[(long)gm * Nc + gn];
                    C[(long)gm * Nc + gn] = v;
                }
            }
        }
    }
}

// Flash-style fused MHA attention.
// Grid (7 q-tiles, 4 heads, 64 batches), block 256 (16x16 microtile threads).
// Per block: Q-tile [64x64] staged transposed; loop over 7 j-tiles: stage
// K^T/V/adj, S=QK^T (reg microtile), mask+online softmax, O += P@V.
__global__ __launch_bounds__(256) void mha_flash(
    const float* __restrict__ q, const float* __restrict__ k,
    const float* __restrict__ v, const float* __restrict__ adj,
    float* __restrict__ ctx)
{
    const int it = blockIdx.x;
    const int h  = blockIdx.y;
    const int b  = blockIdx.z;
    const int i0 = it * 64;
    const int tid = threadIdx.x;
    const int tx = tid & 15, ty = tid >> 4;

    __shared__ float Qs[64][68];   // [d][r]   (Q^T)
    __shared__ float Ks[64][68];   // [d][j]   (K^T)
    __shared__ float Vs[64][68];   // [j][d]
    __shared__ float Ps[64][68];   // adj tile [r][j], then P^T [j][r]
    __shared__ float red[64][17];
    __shared__ float mrow[64];
    __shared__ float arow[64];

    const long base_q = ((long)b * 400 + i0) * 256 + h * 64;
    for (int idx = tid; idx < 1024; idx += 256) {
        const int r = idx >> 4, d4 = idx & 15;
        float4 qv = make_float4(0.f, 0.f, 0.f, 0.f);
        if (i0 + r < 400)
            qv = *reinterpret_cast<const float4*>(q + base_q + (long)r * 256 + d4 * 4);
        Qs[d4 * 4 + 0][r] = qv.x;
        Qs[d4 * 4 + 1][r] = qv.y;
        Qs[d4 * 4 + 2][r] = qv.z;
        Qs[d4 * 4 + 3][r] = qv.w;
    }
    if (tid < 64) mrow[tid] = -3.0e38f;

    float o[4][4] = {};
    float lsum[4] = {0.f, 0.f, 0.f, 0.f};

    for (int jt = 0; jt < 7; ++jt) {
        const int j0 = jt * 64;
        __syncthreads();   // prev-tile LDS reads done (also covers Qs/mrow init)

        const long base_k = ((long)b * 400 + j0) * 256 + h * 64;
        for (int idx = tid; idx < 1024; idx += 256) {
            const int jr = idx >> 4, d4 = idx & 15;
            float4 kv = make_float4(0.f, 0.f, 0.f, 0.f);
            float4 vv = make_float4(0.f, 0.f, 0.f, 0.f);
            if (j0 + jr < 400) {
                kv = *reinterpret_cast<const float4*>(k + base_k + (long)jr * 256 + d4 * 4);
                vv = *reinterpret_cast<const float4*>(v + base_k + (long)jr * 256 + d4 * 4);
            }
            Ks[d4 * 4 + 0][jr] = kv.x;
            Ks[d4 * 4 + 1][jr] = kv.y;
            Ks[d4 * 4 + 2][jr] = kv.z;
            Ks[d4 * 4 + 3][jr] = kv.w;
            *reinterpret_cast<float4*>(&Vs[jr][d4 * 4]) = vv;
            // adj tile: rows i0+jr, cols j0+d4*4..+3  (400%4==0 -> float4-safe)
            float4 av = make_float4(0.f, 0.f, 0.f, 0.f);
            if (i0 + jr < 400 && j0 + d4 * 4 < 400)
                av = *reinterpret_cast<const float4*>(adj + ((long)b * 400 + i0 + jr) * 400 + j0 + d4 * 4);
            *reinterpret_cast<float4*>(&Ps[jr][d4 * 4]) = av;
        }
        __syncthreads();

        // S = Q @ K^T  (rows R=ty*4+i, cols J=tx*4+jj)
        float s[4][4] = {};
#pragma unroll
        for (int kk = 0; kk < 64; ++kk) {
            const float4 aq = *reinterpret_cast<const float4*>(&Qs[kk][ty * 4]);
            const float4 bk2 = *reinterpret_cast<const float4*>(&Ks[kk][tx * 4]);
            const float a4[4] = {aq.x, aq.y, aq.z, aq.w};
            const float b4[4] = {bk2.x, bk2.y, bk2.z, bk2.w};
#pragma unroll
            for (int i = 0; i < 4; ++i)
#pragma unroll
                for (int jj = 0; jj < 4; ++jj)
                    s[i][jj] += a4[i] * b4[jj];
        }

        // scale + mask + per-thread row max
        float lm[4];
#pragma unroll
        for (int i = 0; i < 4; ++i) {
            lm[i] = -3.0e38f;
#pragma unroll
            for (int jj = 0; jj < 4; ++jj) {
                float e = s[i][jj] * 0.125f;
                if (!(Ps[ty * 4 + i][tx * 4 + jj] > 0.f)) e = NEGBIG;
                s[i][jj] = e;
                lm[i] = fmaxf(lm[i], e);
            }
            red[ty * 4 + i][tx] = lm[i];
        }
        __syncthreads();

        if (tid < 64) {
            float tm = red[tid][0];
#pragma unroll
            for (int t = 1; t < 16; ++t) tm = fmaxf(tm, red[tid][t]);
            const float mo = mrow[tid];
            const float mn = fmaxf(mo, tm);
            arow[tid] = __expf(mo - mn);
            mrow[tid] = mn;
        }
        __syncthreads();

        // rescale O/lsum, compute P = exp(s - m), store P^T to LDS
#pragma unroll
        for (int i = 0; i < 4; ++i) {
            const int r = ty * 4 + i;
            const float al = arow[r];
            const float mn = mrow[r];
            lsum[i] *= al;
#pragma unroll
            for (int jj = 0; jj < 4; ++jj) o[i][jj] *= al;
            float psum = 0.f;
#pragma unroll
            for (int jj = 0; jj < 4; ++jj) {
                const float p = __expf(s[i][jj] - mn);
                psum += p;
                Ps[tx * 4 + jj][r] = p;   // overwrite adj tile (consumed)
            }
            lsum[i] += psum;
        }
        __syncthreads();

        // O += P @ V
#pragma unroll
        for (int kk = 0; kk < 64; ++kk) {
            const float4 ap = *reinterpret_cast<const float4*>(&Ps[kk][ty * 4]);
            const float4 bv = *reinterpret_cast<const float4*>(&Vs[kk][tx * 4]);
            const float a4[4] = {ap.x, ap.y, ap.z, ap.w};
            const float b4[4] = {bv.x, bv.y, bv.z, bv.w};
#pragma unroll
            for (int i = 0; i < 4; ++i)
#pragma unroll
                for (int jj = 0; jj < 4; ++jj)
                    o[i][jj] += a4[i] * b4[jj];
        }
    }

    // final l reduction and write-out
    __syncthreads();
#pragma unroll
    for (int i = 0; i < 4; ++i) red[ty * 4 + i][tx] = lsum[i];
    __syncthreads();
    if (tid < 64) {
        float sum = red[tid][0];
#pragma unroll
        for (int t = 1; t < 16; ++t) sum += red[tid][t];
        arow[tid] = 1.f / sum;
    }
    __syncthreads();
#pragma unroll
    for (int i = 0; i < 4; ++i) {
        const int r = ty * 4 + i;
        const int gi = i0 + r;
        if (gi < 400) {
            const float inv = arow[r];
#pragma unroll
            for (int jj = 0; jj < 4; ++jj)
                ctx[((long)b * 400 + gi) * 256 + h * 64 + tx * 4 + jj] = o[i][jj] * inv;
        }
    }
}

// src[r] = h[r,:F].a[:F]; dst[r] = h[r,:F].a[F:2F]. One wave per row.
__global__ __launch_bounds__(256) void gat_srcdst(
    const float* __restrict__ h, const float* __restrict__ a,
    float* __restrict__ src, float* __restrict__ dst, int F)
{
    const int row = blockIdx.x * 4 + (threadIdx.x >> 6);
    const int lane = threadIdx.x & 63;
    const float* hp = h + (long)row * F;
    float s = 0.f, d = 0.f;
    for (int f = lane; f < F; f += 64) {
        const float hv = hp[f];
        s += hv * a[f];
        d += hv * a[F + f];
    }
    s = wave_sum(s);
    d = wave_sum(d);
    if (lane == 0) { src[row] = s; dst[row] = d; }
}

// attn[row, :] = softmax_j(mask(leaky_relu(src_i + dst_j, 0.2))). One wave per row.
__global__ __launch_bounds__(256) void gat_attn(
    const float* __restrict__ src, const float* __restrict__ dst,
    const float* __restrict__ adj, float* __restrict__ attn)
{
    const int row = blockIdx.x * 4 + (threadIdx.x >> 6);   // b*400+i
    const int b = row / 400;
    const int lane = threadIdx.x & 63;
    const float si = src[row];
    const float* db = dst + (long)b * 400;
    const float* adjrow = adj + (long)row * 400;

    float e[7];
    float mx = -3.0e38f;
#pragma unroll
    for (int t = 0; t < 7; ++t) {
        const int j = lane + 64 * t;
        float v = -3.0e38f;
        if (j < 400) {
            v = si + db[j];
            v = (v > 0.f) ? v : 0.2f * v;
            if (!(adjrow[j] > 0.f)) v = NEGBIG;
        }
        e[t] = v;
        mx = fmaxf(mx, v);
    }
    mx = wave_max(mx);

    float p[7];
    float sum = 0.f;
#pragma unroll
    for (int t = 0; t < 7; ++t) {
        const int j = lane + 64 * t;
        if (j < 400) {
            p[t] = __expf(e[t] - mx);
            sum += p[t];
        }
    }
    sum = wave_sum(sum);
    const float inv = 1.f / sum;
#pragma unroll
    for (int t = 0; t < 7; ++t) {
        const int j = lane + 64 * t;
        if (j < 400) attn[(long)row * 400 + j] = p[t] * inv;
    }
}

// LayerNorm over last dim F (+optional ELU). One wave per row.
template<int F, bool ELU>
__global__ __launch_bounds__(256) void ln_kernel(
    const float* __restrict__ in, const float* __restrict__ g,
    const float* __restrict__ b, float* __restrict__ out)
{
    const int row = blockIdx.x * 4 + (threadIdx.x >> 6);
    const int lane = threadIdx.x & 63;
    constexpr int PER = F / 64;
    const float* ip = in + (long)row * F;

    float v[PER];
    float s = 0.f;
#pragma unroll
    for (int t = 0; t < PER; ++t) {
        v[t] = ip[lane + 64 * t];
        s += v[t];
    }
    s = wave_sum(s);
    const float mean = s * (1.f / F);
    float vs = 0.f;
#pragma unroll
    for (int t = 0; t < PER; ++t) {
        const float d = v[t] - mean;
        vs += d * d;
    }
    vs = wave_sum(vs);
    const float rstd = rsqrtf(vs * (1.f / F) + 1e-5f);
#pragma unroll
    for (int t = 0; t < PER; ++t) {
        const int col = lane + 64 * t;
        float y = (v[t] - mean) * rstd * g[col] + b[col];
        if (ELU) y = (y > 0.f) ? y : expm1f(y);
        out[(long)row * F + col] = y;
    }
}

extern "C" void kernel_launch(void* const* d_in, const int* in_sizes, int n_in,
                              void* d_out, int out_size, void* d_ws, size_t ws_size,
                              hipStream_t stream) {
    const float* x    = (const float*)d_in[0];
    const float* adj  = (const float*)d_in[1];
    const float* Wq   = (const float*)d_in[2];
    const float* bq   = (const float*)d_in[3];
    const float* Wk   = (const float*)d_in[4];
    const float* bk   = (const float*)d_in[5];
    const float* Wv   = (const float*)d_in[6];
    const float* bv   = (const float*)d_in[7];
    const float* Wo   = (const float*)d_in[8];
    const float* bo   = (const float*)d_in[9];
    const float* g1W  = (const float*)d_in[10];
    const float* g1a  = (const float*)d_in[11];
    const float* g2W  = (const float*)d_in[12];
    const float* g2a  = (const float*)d_in[13];
    const float* g3W  = (const float*)d_in[14];
    const float* g3a  = (const float*)d_in[15];
    const float* r1W  = (const float*)d_in[16];
    const float* r1b  = (const float*)d_in[17];
    const float* r2W  = (const float*)d_in[18];
    const float* r2b  = (const float*)d_in[19];
    const float* r3W  = (const float*)d_in[20];
    const float* r3b  = (const float*)d_in[21];
    const float* ln1g = (const float*)d_in[22];
    const float* ln1b = (const float*)d_in[23];
    const float* ln2g = (const float*)d_in[24];
    const float* ln2b = (const float*)d_in[25];
    const float* ln3g = (const float*)d_in[26];
    const float* ln3b = (const float*)d_in[27];

    float* out_x = (float*)d_out;              // [25600,128]
    float* attn1 = out_x + 3276800;            // [64,400,400]
    float* attn2 = attn1 + 10240000;
    float* attn3 = attn2 + 10240000;

    float* bufA = (float*)d_ws;                // q / h
    float* bufB = bufA + 6553600;              // k / res-accum
    float* bufC = bufB + 6553600;              // v / x3
    float* bufD = bufC + 6553600;              // ctx / x2
    float* srcb = bufD + 6553600;              // [25600]
    float* dstb = srcb + 25600;                // [25600]
    // xc (x after MHA residual, [25600,400]) lives in the attn1 output
    // region: it is dead before gat_attn writes attn1.
    float* xc = attn1;

    const dim3 blk(256);
    const int M = 25600;
    auto grid2 = [](int m, int n) { return dim3((unsigned)((n + BN - 1) / BN), (unsigned)((m + BM - 1) / BM), 1); };

    // ---- Phase 1: MHA ----
    gemm_f32<true, false, false><<<grid2(M, 256), blk, 0, stream>>>(x, Wq, bq, nullptr, bufA, M, 400, 256, 0, 0, 0);
    gemm_f32<true, false, false><<<grid2(M, 256), blk, 0, stream>>>(x, Wk, bk, nullptr, bufB, M, 400, 256, 0, 0, 0);
    gemm_f32<true, false, false><<<grid2(M, 256), blk, 0, stream>>>(x, Wv, bv, nullptr, bufC, M, 400, 256, 0, 0, 0);
    mha_flash<<<dim3(7, 4, 64), blk, 0, stream>>>(bufA, bufB, bufC, adj, bufD);
    gemm_f32<true, false, true><<<grid2(M, 400), blk, 0, stream>>>(bufD, Wo, bo, x, xc, M, 256, 400, 0, 0, 0);

    // ---- Phase 2: GAT1 (Fin=400, F=256) ----
    gemm_f32<false, false, false><<<grid2(M, 256), blk, 0, stream>>>(xc, g1W, nullptr, nullptr, bufA, M, 400, 256, 0, 0, 0);
    gemm_f32<true, false, false><<<grid2(M, 256), blk, 0, stream>>>(xc, r1W, r1b, nullptr, bufB, M, 400, 256, 0, 0, 0);
    gat_srcdst<<<dim3(6400), blk, 0, stream>>>(bufA, g1a, srcb, dstb, 256);
    gat_attn<<<dim3(6400), blk, 0, stream>>>(srcb, dstb, adj, attn1);   // xc dead from here
    gemm_f32<false, true, false><<<dim3(4, 7, 64), blk, 0, stream>>>(attn1, bufA, nullptr, nullptr, bufB, 400, 400, 256, 160000, 102400, 102400);
    ln_kernel<256, true><<<dim3(6400), blk, 0, stream>>>(bufB, ln1g, ln1b, bufD);

    // ---- Phase 3: GAT2 (256 -> 256) ----
    gemm_f32<false, false, false><<<grid2(M, 256), blk, 0, stream>>>(bufD, g2W, nullptr, nullptr, bufA, M, 256, 256, 0, 0, 0);
    gemm_f32<true, false, false><<<grid2(M, 256), blk, 0, stream>>>(bufD, r2W, r2b, nullptr, bufB, M, 256, 256, 0, 0, 0);
    gat_srcdst<<<dim3(6400), blk, 0, stream>>>(bufA, g2a, srcb, dstb, 256);
    gat_attn<<<dim3(6400), blk, 0, stream>>>(srcb, dstb, adj, attn2);
    gemm_f32<false, true, false><<<dim3(4, 7, 64), blk, 0, stream>>>(attn2, bufA, nullptr, nullptr, bufB, 400, 400, 256, 160000, 102400, 102400);
    ln_kernel<256, true><<<dim3(6400), blk, 0, stream>>>(bufB, ln2g, ln2b, bufC);

    // ---- Phase 4: GAT3 (256 -> 128) ----
    gemm_f32<false, false, false><<<grid2(M, 128), blk, 0, stream>>>(bufC, g3W, nullptr, nullptr, bufA, M, 256, 128, 0, 0, 0);
    gemm_f32<true, false, false><<<grid2(M, 128), blk, 0, stream>>>(bufC, r3W, r3b, nullptr, bufB, M, 256, 128, 0, 0, 0);
    gat_srcdst<<<dim3(6400), blk, 0, stream>>>(bufA, g3a, srcb, dstb, 128);
    gat_attn<<<dim3(6400), blk, 0, stream>>>(srcb, dstb, adj, attn3);
    gemm_f32<false, true, false><<<dim3(2, 7, 64), blk, 0, stream>>>(attn3, bufA, nullptr, nullptr, bufB, 400, 400, 128, 160000, 51200, 51200);
    ln_kernel<128, false><<<dim3(6400), blk, 0, stream>>>(bufB, ln3g, ln3b, out_x);
}

// Round 6
// 1029.852 us; speedup vs baseline: 3.2293x; 1.6094x over previous
//
#include <hip/hip_runtime.h>

// GraphEncoder: MHA + 3×(GAT + residual-proj + LN[+ELU]).
// B=64, N=400, D=400, Hd=256, E=128, H=4, hd=64.
// GEMMs: bf16 MFMA (fp32 accum); softmax/LN/epilogues fp32.
// d_out layout (f32): x_final [64*400*128] | attn1 [64*400*400] | attn2 | attn3

#define NEGBIG (-1e9f)

typedef __attribute__((ext_vector_type(8))) short bf16x8;
typedef __attribute__((ext_vector_type(4))) float f32x4;

__device__ inline unsigned short f2bf(float f) {
    unsigned u = __builtin_bit_cast(unsigned, f);
    u += 0x7fffu + ((u >> 16) & 1u);          // RNE
    return (unsigned short)(u >> 16);
}

__device__ inline float wave_max(float v) {
#pragma unroll
    for (int off = 32; off >= 1; off >>= 1)
        v = fmaxf(v, __shfl_xor(v, off, 64));
    return v;
}
__device__ inline float wave_sum(float v) {
#pragma unroll
    for (int off = 32; off >= 1; off >>= 1)
        v += __shfl_xor(v, off, 64);
    return v;
}

// ---------------------------------------------------------------------------
// Transpose + f32->bf16: out[c][r] = bf16(in[r][c]).  in:[R][C] f32, out:[C][R] bf16.
// Batched via blockIdx.z (sIn/sOut element strides). Requires R%4==0, C%4==0.
__global__ __launch_bounds__(256) void transpose_to_bf16(
    const float* __restrict__ in, unsigned short* __restrict__ out,
    int R, int C, long sIn, long sOut)
{
    in  += (long)blockIdx.z * sIn;
    out += (long)blockIdx.z * sOut;
    __shared__ float t[32][33];
    const int r0 = blockIdx.y * 32, c0 = blockIdx.x * 32;
    const int tid = threadIdx.x;

    const int row = tid >> 3, c4 = tid & 7;
    float4 v = make_float4(0.f, 0.f, 0.f, 0.f);
    if (r0 + row < R && c0 + c4 * 4 < C)
        v = *reinterpret_cast<const float4*>(&in[(long)(r0 + row) * C + c0 + c4 * 4]);
    t[row][c4 * 4 + 0] = v.x;
    t[row][c4 * 4 + 1] = v.y;
    t[row][c4 * 4 + 2] = v.z;
    t[row][c4 * 4 + 3] = v.w;
    __syncthreads();

    const int oc = tid >> 3, r4 = tid & 7;
    if (c0 + oc < C && r0 + r4 * 4 < R) {
        ushort4 o;
        o.x = f2bf(t[r4 * 4 + 0][oc]);
        o.y = f2bf(t[r4 * 4 + 1][oc]);
        o.z = f2bf(t[r4 * 4 + 2][oc]);
        o.w = f2bf(t[r4 * 4 + 3][oc]);
        *reinterpret_cast<ushort4*>(&out[(long)(c0 + oc) * R + r0 + r4 * 4]) = o;
    }
}

// ---------------------------------------------------------------------------
// C[M,Nc] = A[M,K](f32, cvt to bf16) @ BT[Nc,K](bf16)  (+bias)(+resid)(+=C)
// Tile 64x128x32, 256 threads = 4 waves (2x2), each wave 32x64 via
// mfma_f32_16x16x32_bf16 (A-frag: row=l&15,k=(l>>4)*8+j; B-frag: col=l&15;
// C/D: col=lane&15, row=(lane>>4)*4+reg — learn_hip m89/m91 verified).
// Batched via blockIdx.z. K arbitrary (zero-padded in LDS); K%8==0 required.
template<bool BIAS, bool ACCUM, bool RESID>
__global__ __launch_bounds__(256) void gemm_mfma(
    const float* __restrict__ A, const unsigned short* __restrict__ BT,
    const float* __restrict__ bias, const float* __restrict__ resid,
    float* __restrict__ C, int M, int K, int Nc,
    long sA, long sBT, long sC)
{
    const int bz = blockIdx.z;
    A  += (long)bz * sA;
    BT += (long)bz * sBT;
    C  += (long)bz * sC;
    const float* Rp = RESID ? (resid + (long)bz * sC) : nullptr;

    __shared__ short As[64][40];    // [m][k], +8 bf16 pad (row stride 80B)
    __shared__ short Bs[128][40];   // [n][k]

    const int tid = threadIdx.x;
    const int lane = tid & 63, wave = tid >> 6;
    const int wm = wave >> 1, wn = wave & 1;
    const int m0 = blockIdx.y * 64, n0 = blockIdx.x * 128;

    f32x4 acc[2][4] = {};

    const int nk = (K + 31) / 32;
    for (int kt = 0; kt < nk; ++kt) {
        const int k0 = kt * 32;
        __syncthreads();
        // stage A: 64 rows x 8 float4
#pragma unroll
        for (int p = 0; p < 2; ++p) {
            const int idx = tid + p * 256;
            const int row = idx >> 3, k4 = idx & 7;
            const int gm = m0 + row, gk = k0 + k4 * 4;
            float4 av = make_float4(0.f, 0.f, 0.f, 0.f);
            if (gm < M && gk < K)
                av = *reinterpret_cast<const float4*>(&A[(long)gm * K + gk]);
            ushort4 h4;
            h4.x = f2bf(av.x); h4.y = f2bf(av.y); h4.z = f2bf(av.z); h4.w = f2bf(av.w);
            *reinterpret_cast<ushort4*>(&As[row][k4 * 4]) = h4;
        }
        // stage B: 128 rows x 4 x 16B (8 bf16)
#pragma unroll
        for (int p = 0; p < 2; ++p) {
            const int idx = tid + p * 256;
            const int n = idx >> 2, k8 = idx & 3;
            const int gn = n0 + n, gk = k0 + k8 * 8;
            uint4 bv = make_uint4(0u, 0u, 0u, 0u);
            if (gn < Nc && gk < K)
                bv = *reinterpret_cast<const uint4*>(&BT[(long)gn * K + gk]);
            *reinterpret_cast<uint4*>(&Bs[n][k8 * 8]) = bv;
        }
        __syncthreads();

        const int fr = lane & 15, fkb = (lane >> 4) * 8;
        bf16x8 a[2], b[4];
#pragma unroll
        for (int i = 0; i < 2; ++i)
            a[i] = *reinterpret_cast<const bf16x8*>(&As[wm * 32 + i * 16 + fr][fkb]);
#pragma unroll
        for (int j = 0; j < 4; ++j)
            b[j] = *reinterpret_cast<const bf16x8*>(&Bs[wn * 64 + j * 16 + fr][fkb]);
#pragma unroll
        for (int i = 0; i < 2; ++i)
#pragma unroll
            for (int j = 0; j < 4; ++j)
                acc[i][j] = __builtin_amdgcn_mfma_f32_16x16x32_bf16(a[i], b[j], acc[i][j], 0, 0, 0);
    }

    // epilogue (fp32)
    const int fr = lane & 15, rg = lane >> 4;
#pragma unroll
    for (int i = 0; i < 2; ++i) {
#pragma unroll
        for (int j = 0; j < 4; ++j) {
#pragma unroll
            for (int r = 0; r < 4; ++r) {
                const int gm = m0 + wm * 32 + i * 16 + rg * 4 + r;
                const int gn = n0 + wn * 64 + j * 16 + fr;
                if (gm < M && gn < Nc) {
                    float v = acc[i][j][r];
                    if (BIAS)  v += bias[gn];
                    if (RESID) v += Rp[(long)gm * Nc + gn];
                    if (ACCUM) v += C[(long)gm * Nc + gn];
                    C[(long)gm * Nc + gn] = v;
                }
            }
        }
    }
}

// ---------------------------------------------------------------------------
// Flash-style fused MHA attention (fp32). Grid (7 q-tiles, 4 heads, 64 batches).
__global__ __launch_bounds__(256) void mha_flash(
    const float* __restrict__ q, const float* __restrict__ k,
    const float* __restrict__ v, const float* __restrict__ adj,
    float* __restrict__ ctx)
{
    const int it = blockIdx.x;
    const int h  = blockIdx.y;
    const int b  = blockIdx.z;
    const int i0 = it * 64;
    const int tid = threadIdx.x;
    const int tx = tid & 15, ty = tid >> 4;

    __shared__ float Qs[64][68];   // [d][r]   (Q^T)
    __shared__ float Ks[64][68];   // [d][j]   (K^T)
    __shared__ float Vs[64][68];   // [j][d]
    __shared__ float Ps[64][68];   // adj tile [r][j], then P^T [j][r]
    __shared__ float red[64][17];
    __shared__ float mrow[64];
    __shared__ float arow[64];

    const long base_q = ((long)b * 400 + i0) * 256 + h * 64;
    for (int idx = tid; idx < 1024; idx += 256) {
        const int r = idx >> 4, d4 = idx & 15;
        float4 qv = make_float4(0.f, 0.f, 0.f, 0.f);
        if (i0 + r < 400)
            qv = *reinterpret_cast<const float4*>(q + base_q + (long)r * 256 + d4 * 4);
        Qs[d4 * 4 + 0][r] = qv.x;
        Qs[d4 * 4 + 1][r] = qv.y;
        Qs[d4 * 4 + 2][r] = qv.z;
        Qs[d4 * 4 + 3][r] = qv.w;
    }
    if (tid < 64) mrow[tid] = -3.0e38f;

    float o[4][4] = {};
    float lsum[4] = {0.f, 0.f, 0.f, 0.f};

    for (int jt = 0; jt < 7; ++jt) {
        const int j0 = jt * 64;
        __syncthreads();

        const long base_k = ((long)b * 400 + j0) * 256 + h * 64;
        for (int idx = tid; idx < 1024; idx += 256) {
            const int jr = idx >> 4, d4 = idx & 15;
            float4 kv = make_float4(0.f, 0.f, 0.f, 0.f);
            float4 vv = make_float4(0.f, 0.f, 0.f, 0.f);
            if (j0 + jr < 400) {
                kv = *reinterpret_cast<const float4*>(k + base_k + (long)jr * 256 + d4 * 4);
                vv = *reinterpret_cast<const float4*>(v + base_k + (long)jr * 256 + d4 * 4);
            }
            Ks[d4 * 4 + 0][jr] = kv.x;
            Ks[d4 * 4 + 1][jr] = kv.y;
            Ks[d4 * 4 + 2][jr] = kv.z;
            Ks[d4 * 4 + 3][jr] = kv.w;
            *reinterpret_cast<float4*>(&Vs[jr][d4 * 4]) = vv;
            float4 av = make_float4(0.f, 0.f, 0.f, 0.f);
            if (i0 + jr < 400 && j0 + d4 * 4 < 400)
                av = *reinterpret_cast<const float4*>(adj + ((long)b * 400 + i0 + jr) * 400 + j0 + d4 * 4);
            *reinterpret_cast<float4*>(&Ps[jr][d4 * 4]) = av;
        }
        __syncthreads();

        float s[4][4] = {};
#pragma unroll
        for (int kk = 0; kk < 64; ++kk) {
            const float4 aq = *reinterpret_cast<const float4*>(&Qs[kk][ty * 4]);
            const float4 bk2 = *reinterpret_cast<const float4*>(&Ks[kk][tx * 4]);
            const float a4[4] = {aq.x, aq.y, aq.z, aq.w};
            const float b4[4] = {bk2.x, bk2.y, bk2.z, bk2.w};
#pragma unroll
            for (int i = 0; i < 4; ++i)
#pragma unroll
                for (int jj = 0; jj < 4; ++jj)
                    s[i][jj] += a4[i] * b4[jj];
        }

        float lm[4];
#pragma unroll
        for (int i = 0; i < 4; ++i) {
            lm[i] = -3.0e38f;
#pragma unroll
            for (int jj = 0; jj < 4; ++jj) {
                float e = s[i][jj] * 0.125f;
                if (!(Ps[ty * 4 + i][tx * 4 + jj] > 0.f)) e = NEGBIG;
                s[i][jj] = e;
                lm[i] = fmaxf(lm[i], e);
            }
            red[ty * 4 + i][tx] = lm[i];
        }
        __syncthreads();

        if (tid < 64) {
            float tm = red[tid][0];
#pragma unroll
            for (int t = 1; t < 16; ++t) tm = fmaxf(tm, red[tid][t]);
            const float mo = mrow[tid];
            const float mn = fmaxf(mo, tm);
            arow[tid] = __expf(mo - mn);
            mrow[tid] = mn;
        }
        __syncthreads();

#pragma unroll
        for (int i = 0; i < 4; ++i) {
            const int r = ty * 4 + i;
            const float al = arow[r];
            const float mn = mrow[r];
            lsum[i] *= al;
#pragma unroll
            for (int jj = 0; jj < 4; ++jj) o[i][jj] *= al;
            float psum = 0.f;
#pragma unroll
            for (int jj = 0; jj < 4; ++jj) {
                const float p = __expf(s[i][jj] - mn);
                psum += p;
                Ps[tx * 4 + jj][r] = p;
            }
            lsum[i] += psum;
        }
        __syncthreads();

#pragma unroll
        for (int kk = 0; kk < 64; ++kk) {
            const float4 ap = *reinterpret_cast<const float4*>(&Ps[kk][ty * 4]);
            const float4 bv = *reinterpret_cast<const float4*>(&Vs[kk][tx * 4]);
            const float a4[4] = {ap.x, ap.y, ap.z, ap.w};
            const float b4[4] = {bv.x, bv.y, bv.z, bv.w};
#pragma unroll
            for (int i = 0; i < 4; ++i)
#pragma unroll
                for (int jj = 0; jj < 4; ++jj)
                    o[i][jj] += a4[i] * b4[jj];
        }
    }

    __syncthreads();
#pragma unroll
    for (int i = 0; i < 4; ++i) red[ty * 4 + i][tx] = lsum[i];
    __syncthreads();
    if (tid < 64) {
        float sum = red[tid][0];
#pragma unroll
        for (int t = 1; t < 16; ++t) sum += red[tid][t];
        arow[tid] = 1.f / sum;
    }
    __syncthreads();
#pragma unroll
    for (int i = 0; i < 4; ++i) {
        const int r = ty * 4 + i;
        const int gi = i0 + r;
        if (gi < 400) {
            const float inv = arow[r];
#pragma unroll
            for (int jj = 0; jj < 4; ++jj)
                ctx[((long)b * 400 + gi) * 256 + h * 64 + tx * 4 + jj] = o[i][jj] * inv;
        }
    }
}

// src[r] = h[r,:F].a[:F]; dst[r] = h[r,:F].a[F:2F]. One wave per row.
__global__ __launch_bounds__(256) void gat_srcdst(
    const float* __restrict__ h, const float* __restrict__ a,
    float* __restrict__ src, float* __restrict__ dst, int F)
{
    const int row = blockIdx.x * 4 + (threadIdx.x >> 6);
    const int lane = threadIdx.x & 63;
    const float* hp = h + (long)row * F;
    float s = 0.f, d = 0.f;
    for (int f = lane; f < F; f += 64) {
        const float hv = hp[f];
        s += hv * a[f];
        d += hv * a[F + f];
    }
    s = wave_sum(s);
    d = wave_sum(d);
    if (lane == 0) { src[row] = s; dst[row] = d; }
}

// attn[row,:] = softmax_j(mask(leaky_relu(src_i + dst_j, 0.2))). One wave per row.
__global__ __launch_bounds__(256) void gat_attn(
    const float* __restrict__ src, const float* __restrict__ dst,
    const float* __restrict__ adj, float* __restrict__ attn)
{
    const int row = blockIdx.x * 4 + (threadIdx.x >> 6);   // b*400+i
    const int b = row / 400;
    const int lane = threadIdx.x & 63;
    const float si = src[row];
    const float* db = dst + (long)b * 400;
    const float* adjrow = adj + (long)row * 400;

    float e[7];
    float mx = -3.0e38f;
#pragma unroll
    for (int t = 0; t < 7; ++t) {
        const int j = lane + 64 * t;
        float v = -3.0e38f;
        if (j < 400) {
            v = si + db[j];
            v = (v > 0.f) ? v : 0.2f * v;
            if (!(adjrow[j] > 0.f)) v = NEGBIG;
        }
        e[t] = v;
        mx = fmaxf(mx, v);
    }
    mx = wave_max(mx);

    float p[7];
    float sum = 0.f;
#pragma unroll
    for (int t = 0; t < 7; ++t) {
        const int j = lane + 64 * t;
        if (j < 400) {
            p[t] = __expf(e[t] - mx);
            sum += p[t];
        }
    }
    sum = wave_sum(sum);
    const float inv = 1.f / sum;
#pragma unroll
    for (int t = 0; t < 7; ++t) {
        const int j = lane + 64 * t;
        if (j < 400) attn[(long)row * 400 + j] = p[t] * inv;
    }
}

// LayerNorm over last dim F (+optional ELU). One wave per row.
template<int F, bool ELU>
__global__ __launch_bounds__(256) void ln_kernel(
    const float* __restrict__ in, const float* __restrict__ g,
    const float* __restrict__ b, float* __restrict__ out)
{
    const int row = blockIdx.x * 4 + (threadIdx.x >> 6);
    const int lane = threadIdx.x & 63;
    constexpr int PER = F / 64;
    const float* ip = in + (long)row * F;

    float v[PER];
    float s = 0.f;
#pragma unroll
    for (int t = 0; t < PER; ++t) {
        v[t] = ip[lane + 64 * t];
        s += v[t];
    }
    s = wave_sum(s);
    const float mean = s * (1.f / F);
    float vs = 0.f;
#pragma unroll
    for (int t = 0; t < PER; ++t) {
        const float d = v[t] - mean;
        vs += d * d;
    }
    vs = wave_sum(vs);
    const float rstd = rsqrtf(vs * (1.f / F) + 1e-5f);
#pragma unroll
    for (int t = 0; t < PER; ++t) {
        const int col = lane + 64 * t;
        float y = (v[t] - mean) * rstd * g[col] + b[col];
        if (ELU) y = (y > 0.f) ? y : expm1f(y);
        out[(long)row * F + col] = y;
    }
}

extern "C" void kernel_launch(void* const* d_in, const int* in_sizes, int n_in,
                              void* d_out, int out_size, void* d_ws, size_t ws_size,
                              hipStream_t stream) {
    const float* x    = (const float*)d_in[0];
    const float* adj  = (const float*)d_in[1];
    const float* Wq   = (const float*)d_in[2];
    const float* bq   = (const float*)d_in[3];
    const float* Wk   = (const float*)d_in[4];
    const float* bk   = (const float*)d_in[5];
    const float* Wv   = (const float*)d_in[6];
    const float* bv   = (const float*)d_in[7];
    const float* Wo   = (const float*)d_in[8];
    const float* bo   = (const float*)d_in[9];
    const float* g1W  = (const float*)d_in[10];
    const float* g1a  = (const float*)d_in[11];
    const float* g2W  = (const float*)d_in[12];
    const float* g2a  = (const float*)d_in[13];
    const float* g3W  = (const float*)d_in[14];
    const float* g3a  = (const float*)d_in[15];
    const float* r1W  = (const float*)d_in[16];
    const float* r1b  = (const float*)d_in[17];
    const float* r2W  = (const float*)d_in[18];
    const float* r2b  = (const float*)d_in[19];
    const float* r3W  = (const float*)d_in[20];
    const float* r3b  = (const float*)d_in[21];
    const float* ln1g = (const float*)d_in[22];
    const float* ln1b = (const float*)d_in[23];
    const float* ln2g = (const float*)d_in[24];
    const float* ln2b = (const float*)d_in[25];
    const float* ln3g = (const float*)d_in[26];
    const float* ln3b = (const float*)d_in[27];

    float* out_x = (float*)d_out;              // [25600,128]
    float* attn1 = out_x + 3276800;            // [64,400,400]
    float* attn2 = attn1 + 10240000;
    float* attn3 = attn2 + 10240000;

    float* bufA = (float*)d_ws;                // q / h
    float* bufB = bufA + 6553600;              // k / res-accum
    float* bufC = bufB + 6553600;              // v / x3 / hT2
    float* bufD = bufC + 6553600;              // ctx / hT1 / x2 / hT3
    float* srcb = bufD + 6553600;              // [25600]
    float* dstb = srcb + 25600;                // [25600]
    // bf16 transposed weights after dstb (~1.6MB)
    unsigned short* wT   = (unsigned short*)(dstb + 25600);
    unsigned short* wTq  = wT;                 // [256][400]
    unsigned short* wTk  = wT + 102400;
    unsigned short* wTv  = wT + 204800;
    unsigned short* wTo  = wT + 307200;        // [400][256]
    unsigned short* wTg1 = wT + 409600;        // [256][400]
    unsigned short* wTr1 = wT + 512000;
    unsigned short* wTg2 = wT + 614400;        // [256][256]
    unsigned short* wTr2 = wT + 679936;
    unsigned short* wTg3 = wT + 745472;        // [128][256]
    unsigned short* wTr3 = wT + 778240;
    // xc (x after MHA residual, [25600,400]) lives in the attn1 output
    // region: dead before gat_attn writes attn1.
    float* xc = attn1;
    // per-layer h^T bf16 [64][Fout][400] in dead f32 buffers
    unsigned short* hT1 = (unsigned short*)bufD;   // ctx dead after proj
    unsigned short* hT2 = (unsigned short*)bufC;   // v dead after flash
    unsigned short* hT3 = (unsigned short*)bufD;   // x2 dead after h3/res3

    const dim3 blk(256);
    const int M = 25600;

    // ---- Phase 0: weight transposes (f32 -> bf16 [N][K]) ----
    transpose_to_bf16<<<dim3(8, 13), blk, 0, stream>>>(Wq,  wTq, 400, 256, 0, 0);
    transpose_to_bf16<<<dim3(8, 13), blk, 0, stream>>>(Wk,  wTk, 400, 256, 0, 0);
    transpose_to_bf16<<<dim3(8, 13), blk, 0, stream>>>(Wv,  wTv, 400, 256, 0, 0);
    transpose_to_bf16<<<dim3(13, 8), blk, 0, stream>>>(Wo,  wTo, 256, 400, 0, 0);
    transpose_to_bf16<<<dim3(8, 13), blk, 0, stream>>>(g1W, wTg1, 400, 256, 0, 0);
    transpose_to_bf16<<<dim3(8, 13), blk, 0, stream>>>(r1W, wTr1, 400, 256, 0, 0);
    transpose_to_bf16<<<dim3(8, 8),  blk, 0, stream>>>(g2W, wTg2, 256, 256, 0, 0);
    transpose_to_bf16<<<dim3(8, 8),  blk, 0, stream>>>(r2W, wTr2, 256, 256, 0, 0);
    transpose_to_bf16<<<dim3(4, 8),  blk, 0, stream>>>(g3W, wTg3, 256, 128, 0, 0);
    transpose_to_bf16<<<dim3(4, 8),  blk, 0, stream>>>(r3W, wTr3, 256, 128, 0, 0);

    // ---- Phase 1: MHA ----
    gemm_mfma<true, false, false><<<dim3(2, 400), blk, 0, stream>>>(x, wTq, bq, nullptr, bufA, M, 400, 256, 0, 0, 0);
    gemm_mfma<true, false, false><<<dim3(2, 400), blk, 0, stream>>>(x, wTk, bk, nullptr, bufB, M, 400, 256, 0, 0, 0);
    gemm_mfma<true, false, false><<<dim3(2, 400), blk, 0, stream>>>(x, wTv, bv, nullptr, bufC, M, 400, 256, 0, 0, 0);
    mha_flash<<<dim3(7, 4, 64), blk, 0, stream>>>(bufA, bufB, bufC, adj, bufD);
    gemm_mfma<true, false, true><<<dim3(4, 400), blk, 0, stream>>>(bufD, wTo, bo, x, xc, M, 256, 400, 0, 0, 0);

    // ---- Phase 2: GAT1 (400 -> 256) ----
    gemm_mfma<false, false, false><<<dim3(2, 400), blk, 0, stream>>>(xc, wTg1, nullptr, nullptr, bufA, M, 400, 256, 0, 0, 0);
    gemm_mfma<true, false, false><<<dim3(2, 400), blk, 0, stream>>>(xc, wTr1, r1b, nullptr, bufB, M, 400, 256, 0, 0, 0);
    gat_srcdst<<<dim3(6400), blk, 0, stream>>>(bufA, g1a, srcb, dstb, 256);
    gat_attn<<<dim3(6400), blk, 0, stream>>>(srcb, dstb, adj, attn1);   // xc dead
    transpose_to_bf16<<<dim3(8, 13, 64), blk, 0, stream>>>(bufA, hT1, 400, 256, 102400, 102400);
    gemm_mfma<false, true, false><<<dim3(2, 7, 64), blk, 0, stream>>>(attn1, hT1, nullptr, nullptr, bufB, 400, 400, 256, 160000, 102400, 102400);
    ln_kernel<256, true><<<dim3(6400), blk, 0, stream>>>(bufB, ln1g, ln1b, bufD);  // x2 (overwrites dead hT1)

    // ---- Phase 3: GAT2 (256 -> 256) ----
    gemm_mfma<false, false, false><<<dim3(2, 400), blk, 0, stream>>>(bufD, wTg2, nullptr, nullptr, bufA, M, 256, 256, 0, 0, 0);
    gemm_mfma<true, false, false><<<dim3(2, 400), blk, 0, stream>>>(bufD, wTr2, r2b, nullptr, bufB, M, 256, 256, 0, 0, 0);
    gat_srcdst<<<dim3(6400), blk, 0, stream>>>(bufA, g2a, srcb, dstb, 256);
    gat_attn<<<dim3(6400), blk, 0, stream>>>(srcb, dstb, adj, attn2);
    transpose_to_bf16<<<dim3(8, 13, 64), blk, 0, stream>>>(bufA, hT2, 400, 256, 102400, 102400);
    gemm_mfma<false, true, false><<<dim3(2, 7, 64), blk, 0, stream>>>(attn2, hT2, nullptr, nullptr, bufB, 400, 400, 256, 160000, 102400, 102400);
    ln_kernel<256, true><<<dim3(6400), blk, 0, stream>>>(bufB, ln2g, ln2b, bufC);  // x3 (overwrites dead hT2)

    // ---- Phase 4: GAT3 (256 -> 128) ----
    gemm_mfma<false, false, false><<<dim3(1, 400), blk, 0, stream>>>(bufC, wTg3, nullptr, nullptr, bufA, M, 256, 128, 0, 0, 0);
    gemm_mfma<true, false, false><<<dim3(1, 400), blk, 0, stream>>>(bufC, wTr3, r3b, nullptr, bufB, M, 256, 128, 0, 0, 0);
    gat_srcdst<<<dim3(6400), blk, 0, stream>>>(bufA, g3a, srcb, dstb, 128);
    gat_attn<<<dim3(6400), blk, 0, stream>>>(srcb, dstb, adj, attn3);
    transpose_to_bf16<<<dim3(4, 13, 64), blk, 0, stream>>>(bufA, hT3, 400, 128, 51200, 51200);
    gemm_mfma<false, true, false><<<dim3(1, 7, 64), blk, 0, stream>>>(attn3, hT3, nullptr, nullptr, bufB, 400, 400, 128, 160000, 51200, 51200);
    ln_kernel<128, false><<<dim3(6400), blk, 0, stream>>>(bufB, ln3g, ln3b, out_x);
}

// Round 7
// 882.410 us; speedup vs baseline: 3.7688x; 1.1671x over previous
//
#include <hip/hip_runtime.h>

// GraphEncoder: MHA + 3×(GAT + residual-proj + LN[+ELU]).
// B=64, N=400, D=400, Hd=256, E=128, H=4, hd=64.
// All GEMM-shaped compute on bf16 MFMA (fp32 accum); softmax/LN fp32.
// d_out layout (f32): x_final [64*400*128] | attn1 [64*400*400] | attn2 | attn3

#define NEGBIG (-1e9f)

typedef __attribute__((ext_vector_type(8))) short bf16x8;
typedef __attribute__((ext_vector_type(4))) float f32x4;

__device__ inline unsigned short f2bf(float f) {
    unsigned u = __builtin_bit_cast(unsigned, f);
    u += 0x7fffu + ((u >> 16) & 1u);          // RNE
    return (unsigned short)(u >> 16);
}
__device__ inline float bf2f(unsigned short h) {
    unsigned u = ((unsigned)h) << 16;
    return __builtin_bit_cast(float, u);
}

__device__ inline float wave_max(float v) {
#pragma unroll
    for (int off = 32; off >= 1; off >>= 1)
        v = fmaxf(v, __shfl_xor(v, off, 64));
    return v;
}
__device__ inline float wave_sum(float v) {
#pragma unroll
    for (int off = 32; off >= 1; off >>= 1)
        v += __shfl_xor(v, off, 64);
    return v;
}

// ---------------------------------------------------------------------------
// Transpose + f32->bf16: out[c][r] = bf16(in[r][c]).  in:[R][C] f32, out:[C][R] bf16.
__global__ __launch_bounds__(256) void transpose_to_bf16(
    const float* __restrict__ in, unsigned short* __restrict__ out,
    int R, int C, long sIn, long sOut)
{
    in  += (long)blockIdx.z * sIn;
    out += (long)blockIdx.z * sOut;
    __shared__ float t[32][33];
    const int r0 = blockIdx.y * 32, c0 = blockIdx.x * 32;
    const int tid = threadIdx.x;

    const int row = tid >> 3, c4 = tid & 7;
    float4 v = make_float4(0.f, 0.f, 0.f, 0.f);
    if (r0 + row < R && c0 + c4 * 4 < C)
        v = *reinterpret_cast<const float4*>(&in[(long)(r0 + row) * C + c0 + c4 * 4]);
    t[row][c4 * 4 + 0] = v.x;
    t[row][c4 * 4 + 1] = v.y;
    t[row][c4 * 4 + 2] = v.z;
    t[row][c4 * 4 + 3] = v.w;
    __syncthreads();

    const int oc = tid >> 3, r4 = tid & 7;
    if (c0 + oc < C && r0 + r4 * 4 < R) {
        ushort4 o;
        o.x = f2bf(t[r4 * 4 + 0][oc]);
        o.y = f2bf(t[r4 * 4 + 1][oc]);
        o.z = f2bf(t[r4 * 4 + 2][oc]);
        o.w = f2bf(t[r4 * 4 + 3][oc]);
        *reinterpret_cast<ushort4*>(&out[(long)(c0 + oc) * R + r0 + r4 * 4]) = o;
    }
}

// ---------------------------------------------------------------------------
// C[M,Nc] = A[M,K](f32->bf16) @ BT[Nc,K](bf16)  (+bias)(+resid)(+=C)
// Tile 64x128x32, 4 waves (2x2), mfma_f32_16x16x32_bf16.
template<bool BIAS, bool ACCUM, bool RESID>
__global__ __launch_bounds__(256) void gemm_mfma(
    const float* __restrict__ A, const unsigned short* __restrict__ BT,
    const float* __restrict__ bias, const float* __restrict__ resid,
    float* __restrict__ C, int M, int K, int Nc,
    long sA, long sBT, long sC)
{
    const int bz = blockIdx.z;
    A  += (long)bz * sA;
    BT += (long)bz * sBT;
    C  += (long)bz * sC;
    const float* Rp = RESID ? (resid + (long)bz * sC) : nullptr;

    __shared__ short As[64][40];
    __shared__ short Bs[128][40];

    const int tid = threadIdx.x;
    const int lane = tid & 63, wave = tid >> 6;
    const int wm = wave >> 1, wn = wave & 1;
    const int m0 = blockIdx.y * 64, n0 = blockIdx.x * 128;

    f32x4 acc[2][4] = {};

    const int nk = (K + 31) / 32;
    for (int kt = 0; kt < nk; ++kt) {
        const int k0 = kt * 32;
        __syncthreads();
#pragma unroll
        for (int p = 0; p < 2; ++p) {
            const int idx = tid + p * 256;
            const int row = idx >> 3, k4 = idx & 7;
            const int gm = m0 + row, gk = k0 + k4 * 4;
            float4 av = make_float4(0.f, 0.f, 0.f, 0.f);
            if (gm < M && gk < K)
                av = *reinterpret_cast<const float4*>(&A[(long)gm * K + gk]);
            ushort4 h4;
            h4.x = f2bf(av.x); h4.y = f2bf(av.y); h4.z = f2bf(av.z); h4.w = f2bf(av.w);
            *reinterpret_cast<ushort4*>(&As[row][k4 * 4]) = h4;
        }
#pragma unroll
        for (int p = 0; p < 2; ++p) {
            const int idx = tid + p * 256;
            const int n = idx >> 2, k8 = idx & 3;
            const int gn = n0 + n, gk = k0 + k8 * 8;
            uint4 bv = make_uint4(0u, 0u, 0u, 0u);
            if (gn < Nc && gk < K)
                bv = *reinterpret_cast<const uint4*>(&BT[(long)gn * K + gk]);
            *reinterpret_cast<uint4*>(&Bs[n][k8 * 8]) = bv;
        }
        __syncthreads();

        const int fr = lane & 15, fkb = (lane >> 4) * 8;
        bf16x8 a[2], b[4];
#pragma unroll
        for (int i = 0; i < 2; ++i)
            a[i] = *reinterpret_cast<const bf16x8*>(&As[wm * 32 + i * 16 + fr][fkb]);
#pragma unroll
        for (int j = 0; j < 4; ++j)
            b[j] = *reinterpret_cast<const bf16x8*>(&Bs[wn * 64 + j * 16 + fr][fkb]);
#pragma unroll
        for (int i = 0; i < 2; ++i)
#pragma unroll
            for (int j = 0; j < 4; ++j)
                acc[i][j] = __builtin_amdgcn_mfma_f32_16x16x32_bf16(a[i], b[j], acc[i][j], 0, 0, 0);
    }

    const int fr = lane & 15, rg = lane >> 4;
#pragma unroll
    for (int i = 0; i < 2; ++i) {
#pragma unroll
        for (int j = 0; j < 4; ++j) {
#pragma unroll
            for (int r = 0; r < 4; ++r) {
                const int gm = m0 + wm * 32 + i * 16 + rg * 4 + r;
                const int gn = n0 + wn * 64 + j * 16 + fr;
                if (gm < M && gn < Nc) {
                    float v = acc[i][j][r];
                    if (BIAS)  v += bias[gn];
                    if (RESID) v += Rp[(long)gm * Nc + gn];
                    if (ACCUM) v += C[(long)gm * Nc + gn];
                    C[(long)gm * Nc + gn] = v;
                }
            }
        }
    }
}

// ---------------------------------------------------------------------------
// Flash MHA attention on MFMA. Grid (7 q-tiles, 4 heads, 64 batches), 4 waves.
// Wave w owns q-rows [w*16, w*16+16). Per j-tile: stage K/Vt/maskbias bf16,
// S = QK^T via MFMA, online softmax in regs (row = g*4+reg, col = t*16+c),
// P -> wave-private LDS rows -> PV via MFMA.
__global__ __launch_bounds__(256) void mha_flash_mfma(
    const float* __restrict__ q, const float* __restrict__ k,
    const float* __restrict__ v, const float* __restrict__ adj,
    float* __restrict__ ctx)
{
    const int it = blockIdx.x, h = blockIdx.y, b = blockIdx.z;
    const int i0 = it * 64;
    const int tid = threadIdx.x;
    const int lane = tid & 63, w = tid >> 6;
    const int c = lane & 15, g = lane >> 4;

    __shared__ short Qs[64][72];    // [qrow][d]
    __shared__ short Ks[64][72];    // [jrow][d]
    __shared__ short Vt[64][72];    // [d][jrow]
    __shared__ short Ps[64][72];    // [qrow][jrow]  (wave-private row bands)
    __shared__ short Adjs[64][72];  // [qrow][jrow] maskbias: 0 or -1e9 (bf16)

    // stage Q once
    const long base_q = ((long)b * 400 + i0) * 256 + h * 64;
#pragma unroll
    for (int p = 0; p < 4; ++p) {
        const int idx = tid + p * 256;
        const int r = idx >> 4, c4 = idx & 15;
        float4 qv = make_float4(0.f, 0.f, 0.f, 0.f);
        if (i0 + r < 400)
            qv = *reinterpret_cast<const float4*>(q + base_q + (long)r * 256 + c4 * 4);
        ushort4 h4;
        h4.x = f2bf(qv.x); h4.y = f2bf(qv.y); h4.z = f2bf(qv.z); h4.w = f2bf(qv.w);
        *reinterpret_cast<ushort4*>(&Qs[r][c4 * 4]) = h4;
    }

    f32x4 o[4] = {};                                   // [dtile], rows g*4+reg
    float m[4] = {-3e38f, -3e38f, -3e38f, -3e38f};
    float l[4] = {0.f, 0.f, 0.f, 0.f};                 // lane-partial row sums

    for (int jt = 0; jt < 7; ++jt) {
        const int j0 = jt * 64;
        __syncthreads();   // prev iter's LDS reads done

        const long base_k = ((long)b * 400 + j0) * 256 + h * 64;
        // stage K rows + adj maskbias rows
#pragma unroll
        for (int p = 0; p < 4; ++p) {
            const int idx = tid + p * 256;
            const int r = idx >> 4, c4 = idx & 15;
            float4 kv = make_float4(0.f, 0.f, 0.f, 0.f);
            if (j0 + r < 400)
                kv = *reinterpret_cast<const float4*>(k + base_k + (long)r * 256 + c4 * 4);
            ushort4 h4;
            h4.x = f2bf(kv.x); h4.y = f2bf(kv.y); h4.z = f2bf(kv.z); h4.w = f2bf(kv.w);
            *reinterpret_cast<ushort4*>(&Ks[r][c4 * 4]) = h4;

            float4 av = make_float4(0.f, 0.f, 0.f, 0.f);
            if (i0 + r < 400 && j0 + c4 * 4 < 400)
                av = *reinterpret_cast<const float4*>(adj + ((long)b * 400 + i0 + r) * 400 + j0 + c4 * 4);
            ushort4 mb;
            mb.x = f2bf(av.x > 0.f ? 0.f : NEGBIG);
            mb.y = f2bf(av.y > 0.f ? 0.f : NEGBIG);
            mb.z = f2bf(av.z > 0.f ? 0.f : NEGBIG);
            mb.w = f2bf(av.w > 0.f ? 0.f : NEGBIG);
            *reinterpret_cast<ushort4*>(&Adjs[r][c4 * 4]) = mb;
        }
        // stage V transposed (4x4 register blocks)
        {
            const int j4 = tid >> 4, d4 = tid & 15;
            float vv[4][4];
#pragma unroll
            for (int t = 0; t < 4; ++t) {
                float4 vl = make_float4(0.f, 0.f, 0.f, 0.f);
                if (j0 + j4 * 4 + t < 400)
                    vl = *reinterpret_cast<const float4*>(v + base_k + (long)(j4 * 4 + t) * 256 + d4 * 4);
                vv[t][0] = vl.x; vv[t][1] = vl.y; vv[t][2] = vl.z; vv[t][3] = vl.w;
            }
#pragma unroll
            for (int u = 0; u < 4; ++u) {
                ushort4 h4;
                h4.x = f2bf(vv[0][u]); h4.y = f2bf(vv[1][u]);
                h4.z = f2bf(vv[2][u]); h4.w = f2bf(vv[3][u]);
                *reinterpret_cast<ushort4*>(&Vt[d4 * 4 + u][j4 * 4]) = h4;
            }
        }
        __syncthreads();

        // S = Q @ K^T  (wave rows w*16.., 64 cols)
        f32x4 s4[4] = {};
#pragma unroll
        for (int ks = 0; ks < 2; ++ks) {
            const bf16x8 a = *reinterpret_cast<const bf16x8*>(&Qs[w * 16 + c][ks * 32 + g * 8]);
#pragma unroll
            for (int t = 0; t < 4; ++t) {
                const bf16x8 bb = *reinterpret_cast<const bf16x8*>(&Ks[t * 16 + c][ks * 32 + g * 8]);
                s4[t] = __builtin_amdgcn_mfma_f32_16x16x32_bf16(a, bb, s4[t], 0, 0, 0);
            }
        }

        // scale + mask, row max
        float e[4][4];   // [t][reg]
        float pmax[4];
#pragma unroll
        for (int reg = 0; reg < 4; ++reg) {
            const int qr = w * 16 + g * 4 + reg;
            float mx = -3e38f;
#pragma unroll
            for (int t = 0; t < 4; ++t) {
                const float ev = s4[t][reg] * 0.125f + bf2f((unsigned short)Adjs[qr][t * 16 + c]);
                e[t][reg] = ev;
                mx = fmaxf(mx, ev);
            }
            pmax[reg] = mx;
        }
#pragma unroll
        for (int reg = 0; reg < 4; ++reg)
#pragma unroll
            for (int off = 1; off <= 8; off <<= 1)
                pmax[reg] = fmaxf(pmax[reg], __shfl_xor(pmax[reg], off, 64));

        float al[4];
#pragma unroll
        for (int reg = 0; reg < 4; ++reg) {
            const float mn = fmaxf(m[reg], pmax[reg]);
            al[reg] = __expf(m[reg] - mn);
            m[reg] = mn;
        }

        // P = exp(e - m): write bf16 to wave-private Ps rows, keep partial l
#pragma unroll
        for (int reg = 0; reg < 4; ++reg) {
            const int qr = w * 16 + g * 4 + reg;
            float psum = 0.f;
#pragma unroll
            for (int t = 0; t < 4; ++t) {
                const float p = __expf(e[t][reg] - m[reg]);
                psum += p;
                Ps[qr][t * 16 + c] = (short)f2bf(p);
            }
            l[reg] = l[reg] * al[reg] + psum;
        }

        // rescale O, then O += P @ V
#pragma unroll
        for (int dt = 0; dt < 4; ++dt)
#pragma unroll
            for (int reg = 0; reg < 4; ++reg)
                o[dt][reg] *= al[reg];

#pragma unroll
        for (int ks = 0; ks < 2; ++ks) {
            const bf16x8 a = *reinterpret_cast<const bf16x8*>(&Ps[w * 16 + c][ks * 32 + g * 8]);
#pragma unroll
            for (int dt = 0; dt < 4; ++dt) {
                const bf16x8 bb = *reinterpret_cast<const bf16x8*>(&Vt[dt * 16 + c][ks * 32 + g * 8]);
                o[dt] = __builtin_amdgcn_mfma_f32_16x16x32_bf16(a, bb, o[dt], 0, 0, 0);
            }
        }
    }

    // reduce partial l across the 16 col-lanes, write out
#pragma unroll
    for (int reg = 0; reg < 4; ++reg)
#pragma unroll
        for (int off = 1; off <= 8; off <<= 1)
            l[reg] += __shfl_xor(l[reg], off, 64);

#pragma unroll
    for (int reg = 0; reg < 4; ++reg) {
        const int gi = i0 + w * 16 + g * 4 + reg;
        if (gi < 400) {
            const float inv = 1.f / l[reg];
#pragma unroll
            for (int dt = 0; dt < 4; ++dt)
                ctx[((long)b * 400 + gi) * 256 + h * 64 + dt * 16 + c] = o[dt][reg] * inv;
        }
    }
}

// src[r] = h[r,:F].a[:F]; dst[r] = h[r,:F].a[F:2F]. One wave per row.
__global__ __launch_bounds__(256) void gat_srcdst(
    const float* __restrict__ h, const float* __restrict__ a,
    float* __restrict__ src, float* __restrict__ dst, int F)
{
    const int row = blockIdx.x * 4 + (threadIdx.x >> 6);
    const int lane = threadIdx.x & 63;
    const float* hp = h + (long)row * F;
    float s = 0.f, d = 0.f;
    for (int f = lane; f < F; f += 64) {
        const float hv = hp[f];
        s += hv * a[f];
        d += hv * a[F + f];
    }
    s = wave_sum(s);
    d = wave_sum(d);
    if (lane == 0) { src[row] = s; dst[row] = d; }
}

// attn[row,:] = softmax_j(mask(leaky_relu(src_i + dst_j, 0.2))). One wave per row.
__global__ __launch_bounds__(256) void gat_attn(
    const float* __restrict__ src, const float* __restrict__ dst,
    const float* __restrict__ adj, float* __restrict__ attn)
{
    const int row = blockIdx.x * 4 + (threadIdx.x >> 6);   // b*400+i
    const int b = row / 400;
    const int lane = threadIdx.x & 63;
    const float si = src[row];
    const float* db = dst + (long)b * 400;
    const float* adjrow = adj + (long)row * 400;

    float e[7];
    float mx = -3.0e38f;
#pragma unroll
    for (int t = 0; t < 7; ++t) {
        const int j = lane + 64 * t;
        float v = -3.0e38f;
        if (j < 400) {
            v = si + db[j];
            v = (v > 0.f) ? v : 0.2f * v;
            if (!(adjrow[j] > 0.f)) v = NEGBIG;
        }
        e[t] = v;
        mx = fmaxf(mx, v);
    }
    mx = wave_max(mx);

    float p[7];
    float sum = 0.f;
#pragma unroll
    for (int t = 0; t < 7; ++t) {
        const int j = lane + 64 * t;
        if (j < 400) {
            p[t] = __expf(e[t] - mx);
            sum += p[t];
        }
    }
    sum = wave_sum(sum);
    const float inv = 1.f / sum;
#pragma unroll
    for (int t = 0; t < 7; ++t) {
        const int j = lane + 64 * t;
        if (j < 400) attn[(long)row * 400 + j] = p[t] * inv;
    }
}

// LayerNorm over last dim F (+optional ELU). One wave per row.
template<int F, bool ELU>
__global__ __launch_bounds__(256) void ln_kernel(
    const float* __restrict__ in, const float* __restrict__ g,
    const float* __restrict__ b, float* __restrict__ out)
{
    const int row = blockIdx.x * 4 + (threadIdx.x >> 6);
    const int lane = threadIdx.x & 63;
    constexpr int PER = F / 64;
    const float* ip = in + (long)row * F;

    float v[PER];
    float s = 0.f;
#pragma unroll
    for (int t = 0; t < PER; ++t) {
        v[t] = ip[lane + 64 * t];
        s += v[t];
    }
    s = wave_sum(s);
    const float mean = s * (1.f / F);
    float vs = 0.f;
#pragma unroll
    for (int t = 0; t < PER; ++t) {
        const float d = v[t] - mean;
        vs += d * d;
    }
    vs = wave_sum(vs);
    const float rstd = rsqrtf(vs * (1.f / F) + 1e-5f);
#pragma unroll
    for (int t = 0; t < PER; ++t) {
        const int col = lane + 64 * t;
        float y = (v[t] - mean) * rstd * g[col] + b[col];
        if (ELU) y = (y > 0.f) ? y : expm1f(y);
        out[(long)row * F + col] = y;
    }
}

extern "C" void kernel_launch(void* const* d_in, const int* in_sizes, int n_in,
                              void* d_out, int out_size, void* d_ws, size_t ws_size,
                              hipStream_t stream) {
    const float* x    = (const float*)d_in[0];
    const float* adj  = (const float*)d_in[1];
    const float* Wq   = (const float*)d_in[2];
    const float* bq   = (const float*)d_in[3];
    const float* Wk   = (const float*)d_in[4];
    const float* bk   = (const float*)d_in[5];
    const float* Wv   = (const float*)d_in[6];
    const float* bv   = (const float*)d_in[7];
    const float* Wo   = (const float*)d_in[8];
    const float* bo   = (const float*)d_in[9];
    const float* g1W  = (const float*)d_in[10];
    const float* g1a  = (const float*)d_in[11];
    const float* g2W  = (const float*)d_in[12];
    const float* g2a  = (const float*)d_in[13];
    const float* g3W  = (const float*)d_in[14];
    const float* g3a  = (const float*)d_in[15];
    const float* r1W  = (const float*)d_in[16];
    const float* r1b  = (const float*)d_in[17];
    const float* r2W  = (const float*)d_in[18];
    const float* r2b  = (const float*)d_in[19];
    const float* r3W  = (const float*)d_in[20];
    const float* r3b  = (const float*)d_in[21];
    const float* ln1g = (const float*)d_in[22];
    const float* ln1b = (const float*)d_in[23];
    const float* ln2g = (const float*)d_in[24];
    const float* ln2b = (const float*)d_in[25];
    const float* ln3g = (const float*)d_in[26];
    const float* ln3b = (const float*)d_in[27];

    float* out_x = (float*)d_out;              // [25600,128]
    float* attn1 = out_x + 3276800;            // [64,400,400]
    float* attn2 = attn1 + 10240000;
    float* attn3 = attn2 + 10240000;

    float* bufA = (float*)d_ws;                // q / h
    float* bufB = bufA + 6553600;              // k / res-accum
    float* bufC = bufB + 6553600;              // v / x3 / hT2
    float* bufD = bufC + 6553600;              // ctx / hT1 / x2 / hT3
    float* srcb = bufD + 6553600;              // [25600]
    float* dstb = srcb + 25600;                // [25600]
    unsigned short* wT   = (unsigned short*)(dstb + 25600);
    unsigned short* wTq  = wT;                 // [256][400]
    unsigned short* wTk  = wT + 102400;
    unsigned short* wTv  = wT + 204800;
    unsigned short* wTo  = wT + 307200;        // [400][256]
    unsigned short* wTg1 = wT + 409600;        // [256][400]
    unsigned short* wTr1 = wT + 512000;
    unsigned short* wTg2 = wT + 614400;        // [256][256]
    unsigned short* wTr2 = wT + 679936;
    unsigned short* wTg3 = wT + 745472;        // [128][256]
    unsigned short* wTr3 = wT + 778240;
    float* xc = attn1;                         // xc lives in attn1 (dead until gat_attn)
    unsigned short* hT1 = (unsigned short*)bufD;
    unsigned short* hT2 = (unsigned short*)bufC;
    unsigned short* hT3 = (unsigned short*)bufD;

    const dim3 blk(256);
    const int M = 25600;

    // ---- Phase 0: weight transposes (f32 -> bf16 [N][K]) ----
    transpose_to_bf16<<<dim3(8, 13), blk, 0, stream>>>(Wq,  wTq, 400, 256, 0, 0);
    transpose_to_bf16<<<dim3(8, 13), blk, 0, stream>>>(Wk,  wTk, 400, 256, 0, 0);
    transpose_to_bf16<<<dim3(8, 13), blk, 0, stream>>>(Wv,  wTv, 400, 256, 0, 0);
    transpose_to_bf16<<<dim3(13, 8), blk, 0, stream>>>(Wo,  wTo, 256, 400, 0, 0);
    transpose_to_bf16<<<dim3(8, 13), blk, 0, stream>>>(g1W, wTg1, 400, 256, 0, 0);
    transpose_to_bf16<<<dim3(8, 13), blk, 0, stream>>>(r1W, wTr1, 400, 256, 0, 0);
    transpose_to_bf16<<<dim3(8, 8),  blk, 0, stream>>>(g2W, wTg2, 256, 256, 0, 0);
    transpose_to_bf16<<<dim3(8, 8),  blk, 0, stream>>>(r2W, wTr2, 256, 256, 0, 0);
    transpose_to_bf16<<<dim3(4, 8),  blk, 0, stream>>>(g3W, wTg3, 256, 128, 0, 0);
    transpose_to_bf16<<<dim3(4, 8),  blk, 0, stream>>>(r3W, wTr3, 256, 128, 0, 0);

    // ---- Phase 1: MHA ----
    gemm_mfma<true, false, false><<<dim3(2, 400), blk, 0, stream>>>(x, wTq, bq, nullptr, bufA, M, 400, 256, 0, 0, 0);
    gemm_mfma<true, false, false><<<dim3(2, 400), blk, 0, stream>>>(x, wTk, bk, nullptr, bufB, M, 400, 256, 0, 0, 0);
    gemm_mfma<true, false, false><<<dim3(2, 400), blk, 0, stream>>>(x, wTv, bv, nullptr, bufC, M, 400, 256, 0, 0, 0);
    mha_flash_mfma<<<dim3(7, 4, 64), blk, 0, stream>>>(bufA, bufB, bufC, adj, bufD);
    gemm_mfma<true, false, true><<<dim3(4, 400), blk, 0, stream>>>(bufD, wTo, bo, x, xc, M, 256, 400, 0, 0, 0);

    // ---- Phase 2: GAT1 (400 -> 256) ----
    gemm_mfma<false, false, false><<<dim3(2, 400), blk, 0, stream>>>(xc, wTg1, nullptr, nullptr, bufA, M, 400, 256, 0, 0, 0);
    gemm_mfma<true, false, false><<<dim3(2, 400), blk, 0, stream>>>(xc, wTr1, r1b, nullptr, bufB, M, 400, 256, 0, 0, 0);
    gat_srcdst<<<dim3(6400), blk, 0, stream>>>(bufA, g1a, srcb, dstb, 256);
    gat_attn<<<dim3(6400), blk, 0, stream>>>(srcb, dstb, adj, attn1);   // xc dead
    transpose_to_bf16<<<dim3(8, 13, 64), blk, 0, stream>>>(bufA, hT1, 400, 256, 102400, 102400);
    gemm_mfma<false, true, false><<<dim3(2, 7, 64), blk, 0, stream>>>(attn1, hT1, nullptr, nullptr, bufB, 400, 400, 256, 160000, 102400, 102400);
    ln_kernel<256, true><<<dim3(6400), blk, 0, stream>>>(bufB, ln1g, ln1b, bufD);

    // ---- Phase 3: GAT2 (256 -> 256) ----
    gemm_mfma<false, false, false><<<dim3(2, 400), blk, 0, stream>>>(bufD, wTg2, nullptr, nullptr, bufA, M, 256, 256, 0, 0, 0);
    gemm_mfma<true, false, false><<<dim3(2, 400), blk, 0, stream>>>(bufD, wTr2, r2b, nullptr, bufB, M, 256, 256, 0, 0, 0);
    gat_srcdst<<<dim3(6400), blk, 0, stream>>>(bufA, g2a, srcb, dstb, 256);
    gat_attn<<<dim3(6400), blk, 0, stream>>>(srcb, dstb, adj, attn2);
    transpose_to_bf16<<<dim3(8, 13, 64), blk, 0, stream>>>(bufA, hT2, 400, 256, 102400, 102400);
    gemm_mfma<false, true, false><<<dim3(2, 7, 64), blk, 0, stream>>>(attn2, hT2, nullptr, nullptr, bufB, 400, 400, 256, 160000, 102400, 102400);
    ln_kernel<256, true><<<dim3(6400), blk, 0, stream>>>(bufB, ln2g, ln2b, bufC);

    // ---- Phase 4: GAT3 (256 -> 128) ----
    gemm_mfma<false, false, false><<<dim3(1, 400), blk, 0, stream>>>(bufC, wTg3, nullptr, nullptr, bufA, M, 256, 128, 0, 0, 0);
    gemm_mfma<true, false, false><<<dim3(1, 400), blk, 0, stream>>>(bufC, wTr3, r3b, nullptr, bufB, M, 256, 128, 0, 0, 0);
    gat_srcdst<<<dim3(6400), blk, 0, stream>>>(bufA, g3a, srcb, dstb, 128);
    gat_attn<<<dim3(6400), blk, 0, stream>>>(srcb, dstb, adj, attn3);
    transpose_to_bf16<<<dim3(4, 13, 64), blk, 0, stream>>>(bufA, hT3, 400, 128, 51200, 51200);
    gemm_mfma<false, true, false><<<dim3(1, 7, 64), blk, 0, stream>>>(attn3, hT3, nullptr, nullptr, bufB, 400, 400, 128, 160000, 51200, 51200);
    ln_kernel<128, false><<<dim3(6400), blk, 0, stream>>>(bufB, ln3g, ln3b, out_x);
}

// Round 8
// 852.303 us; speedup vs baseline: 3.9020x; 1.0353x over previous
//
#include <hip/hip_runtime.h>

// GraphEncoder: MHA + 3×(GAT + residual-proj + LN[+ELU]).
// B=64, N=400, D=400, Hd=256, E=128, H=4, hd=64.
// All GEMM-shaped compute on bf16 MFMA (fp32 accum); softmax/LN fp32.
// Fused GEMMs: qkv (N=768), g+r per layer (N=512/512/256).
// d_out layout (f32): x_final [64*400*128] | attn1 [64*400*400] | attn2 | attn3

#define NEGBIG (-1e9f)

typedef __attribute__((ext_vector_type(8))) short bf16x8;
typedef __attribute__((ext_vector_type(4))) float f32x4;

__device__ inline unsigned short f2bf(float f) {
    unsigned u = __builtin_bit_cast(unsigned, f);
    u += 0x7fffu + ((u >> 16) & 1u);          // RNE
    return (unsigned short)(u >> 16);
}
__device__ inline float bf2f(unsigned short h) {
    unsigned u = ((unsigned)h) << 16;
    return __builtin_bit_cast(float, u);
}

__device__ inline float wave_max(float v) {
#pragma unroll
    for (int off = 32; off >= 1; off >>= 1)
        v = fmaxf(v, __shfl_xor(v, off, 64));
    return v;
}
__device__ inline float wave_sum(float v) {
#pragma unroll
    for (int off = 32; off >= 1; off >>= 1)
        v += __shfl_xor(v, off, 64);
    return v;
}

// ---------------------------------------------------------------------------
// Concatenated bias vectors (zeros for the g-halves). One block of 256.
__global__ void build_biases(
    float* bqkv, const float* bq, const float* bk, const float* bv,
    float* bgr1, const float* r1b, float* bgr2, const float* r2b,
    float* bgr3, const float* r3b)
{
    const int t = threadIdx.x;
    bqkv[t] = bq[t]; bqkv[256 + t] = bk[t]; bqkv[512 + t] = bv[t];
    bgr1[t] = 0.f; bgr1[256 + t] = r1b[t];
    bgr2[t] = 0.f; bgr2[256 + t] = r2b[t];
    if (t < 128) { bgr3[t] = 0.f; bgr3[128 + t] = r3b[t]; }
}

// ---------------------------------------------------------------------------
// Transpose + f32->bf16: out[c][r] = bf16(in[r][c]).
// in: rows R, cols C, row stride ldIn (elements). out: [C][R] bf16 packed.
__global__ __launch_bounds__(256) void transpose_to_bf16(
    const float* __restrict__ in, unsigned short* __restrict__ out,
    int R, int C, int ldIn, long sIn, long sOut)
{
    in  += (long)blockIdx.z * sIn;
    out += (long)blockIdx.z * sOut;
    __shared__ float t[32][33];
    const int r0 = blockIdx.y * 32, c0 = blockIdx.x * 32;
    const int tid = threadIdx.x;

    const int row = tid >> 3, c4 = tid & 7;
    float4 v = make_float4(0.f, 0.f, 0.f, 0.f);
    if (r0 + row < R && c0 + c4 * 4 < C)
        v = *reinterpret_cast<const float4*>(&in[(long)(r0 + row) * ldIn + c0 + c4 * 4]);
    t[row][c4 * 4 + 0] = v.x;
    t[row][c4 * 4 + 1] = v.y;
    t[row][c4 * 4 + 2] = v.z;
    t[row][c4 * 4 + 3] = v.w;
    __syncthreads();

    const int oc = tid >> 3, r4 = tid & 7;
    if (c0 + oc < C && r0 + r4 * 4 < R) {
        ushort4 o;
        o.x = f2bf(t[r4 * 4 + 0][oc]);
        o.y = f2bf(t[r4 * 4 + 1][oc]);
        o.z = f2bf(t[r4 * 4 + 2][oc]);
        o.w = f2bf(t[r4 * 4 + 3][oc]);
        *reinterpret_cast<ushort4*>(&out[(long)(c0 + oc) * R + r0 + r4 * 4]) = o;
    }
}

// ---------------------------------------------------------------------------
// C[M,Nc] = A[M,K]（f32->bf16) @ BT[Nc,K](bf16)  (+bias)(+resid)(+=C)
// Tile 128x256x32, 512 threads = 8 waves (2x4), wave tile 64x64 via
// mfma_f32_16x16x32_bf16. A row stride ldA, C/resid row stride ldC.
// Batched via blockIdx.z. K%8==0 required; M,Nc guarded.
template<bool BIAS, bool ACCUM, bool RESID>
__global__ __launch_bounds__(512) void gemm_mfma(
    const float* __restrict__ A, const unsigned short* __restrict__ BT,
    const float* __restrict__ bias, const float* __restrict__ resid,
    float* __restrict__ C, int M, int K, int Nc, int ldA, int ldC,
    long sA, long sBT, long sC)
{
    const int bz = blockIdx.z;
    A  += (long)bz * sA;
    BT += (long)bz * sBT;
    C  += (long)bz * sC;
    const float* Rp = RESID ? (resid + (long)bz * sC) : nullptr;

    __shared__ short As[128][40];   // [m][k], +8 pad
    __shared__ short Bs[256][40];   // [n][k]

    const int tid = threadIdx.x;
    const int lane = tid & 63, wave = tid >> 6;
    const int wm = wave >> 2, wn = wave & 3;           // 2 x 4 waves
    const int m0 = blockIdx.y * 128, n0 = blockIdx.x * 256;

    f32x4 acc[4][4] = {};

    const int nk = (K + 31) / 32;
    for (int kt = 0; kt < nk; ++kt) {
        const int k0 = kt * 32;
        __syncthreads();
        // stage A: 128 rows x 8 float4 (f32 -> bf16)
#pragma unroll
        for (int p = 0; p < 2; ++p) {
            const int idx = tid + p * 512;
            const int row = idx >> 3, k4 = idx & 7;
            const int gm = m0 + row, gk = k0 + k4 * 4;
            float4 av = make_float4(0.f, 0.f, 0.f, 0.f);
            if (gm < M && gk < K)
                av = *reinterpret_cast<const float4*>(&A[(long)gm * ldA + gk]);
            ushort4 h4;
            h4.x = f2bf(av.x); h4.y = f2bf(av.y); h4.z = f2bf(av.z); h4.w = f2bf(av.w);
            *reinterpret_cast<ushort4*>(&As[row][k4 * 4]) = h4;
        }
        // stage B: 256 rows x 4 x 16B
#pragma unroll
        for (int p = 0; p < 2; ++p) {
            const int idx = tid + p * 512;
            const int n = idx >> 2, k8 = idx & 3;
            const int gn = n0 + n, gk = k0 + k8 * 8;
            uint4 bv = make_uint4(0u, 0u, 0u, 0u);
            if (gn < Nc && gk < K)
                bv = *reinterpret_cast<const uint4*>(&BT[(long)gn * K + gk]);
            *reinterpret_cast<uint4*>(&Bs[n][k8 * 8]) = bv;
        }
        __syncthreads();

        const int fr = lane & 15, fkb = (lane >> 4) * 8;
        bf16x8 a[4], b[4];
#pragma unroll
        for (int i = 0; i < 4; ++i)
            a[i] = *reinterpret_cast<const bf16x8*>(&As[wm * 64 + i * 16 + fr][fkb]);
#pragma unroll
        for (int j = 0; j < 4; ++j)
            b[j] = *reinterpret_cast<const bf16x8*>(&Bs[wn * 64 + j * 16 + fr][fkb]);
#pragma unroll
        for (int i = 0; i < 4; ++i)
#pragma unroll
            for (int j = 0; j < 4; ++j)
                acc[i][j] = __builtin_amdgcn_mfma_f32_16x16x32_bf16(a[i], b[j], acc[i][j], 0, 0, 0);
    }

    const int fr = lane & 15, rg = lane >> 4;
#pragma unroll
    for (int i = 0; i < 4; ++i) {
#pragma unroll
        for (int j = 0; j < 4; ++j) {
#pragma unroll
            for (int r = 0; r < 4; ++r) {
                const int gm = m0 + wm * 64 + i * 16 + rg * 4 + r;
                const int gn = n0 + wn * 64 + j * 16 + fr;
                if (gm < M && gn < Nc) {
                    float v = acc[i][j][r];
                    if (BIAS)  v += bias[gn];
                    if (RESID) v += Rp[(long)gm * ldC + gn];
                    if (ACCUM) v += C[(long)gm * ldC + gn];
                    C[(long)gm * ldC + gn] = v;
                }
            }
        }
    }
}

// ---------------------------------------------------------------------------
// Flash MHA attention on MFMA. Grid (7 q-tiles, 4 heads, 64 batches), 4 waves.
// qkv fused buffer: row stride ld; q at col 0, k at 256, v at 512 (+h*64).
__global__ __launch_bounds__(256) void mha_flash_mfma(
    const float* __restrict__ qkv, const float* __restrict__ adj,
    float* __restrict__ ctx, int ld)
{
    const int it = blockIdx.x, h = blockIdx.y, b = blockIdx.z;
    const int i0 = it * 64;
    const int tid = threadIdx.x;
    const int lane = tid & 63, w = tid >> 6;
    const int c = lane & 15, g = lane >> 4;

    __shared__ short Qs[64][72];    // [qrow][d]
    __shared__ short Ks[64][72];    // [jrow][d]
    __shared__ short Vt[64][72];    // [d][jrow]
    __shared__ short Ps[64][72];    // [qrow][jrow] wave-private bands
    __shared__ short Adjs[64][72];  // maskbias 0 / -1e9 (bf16)

    const long base_q = ((long)b * 400 + i0) * ld + h * 64;
#pragma unroll
    for (int p = 0; p < 4; ++p) {
        const int idx = tid + p * 256;
        const int r = idx >> 4, c4 = idx & 15;
        float4 qv = make_float4(0.f, 0.f, 0.f, 0.f);
        if (i0 + r < 400)
            qv = *reinterpret_cast<const float4*>(qkv + base_q + (long)r * ld + c4 * 4);
        ushort4 h4;
        h4.x = f2bf(qv.x); h4.y = f2bf(qv.y); h4.z = f2bf(qv.z); h4.w = f2bf(qv.w);
        *reinterpret_cast<ushort4*>(&Qs[r][c4 * 4]) = h4;
    }

    f32x4 o[4] = {};
    float m[4] = {-3e38f, -3e38f, -3e38f, -3e38f};
    float l[4] = {0.f, 0.f, 0.f, 0.f};

    for (int jt = 0; jt < 7; ++jt) {
        const int j0 = jt * 64;
        __syncthreads();

        const long base_k = ((long)b * 400 + j0) * ld + 256 + h * 64;
        const long base_v = base_k + 256;
#pragma unroll
        for (int p = 0; p < 4; ++p) {
            const int idx = tid + p * 256;
            const int r = idx >> 4, c4 = idx & 15;
            float4 kv = make_float4(0.f, 0.f, 0.f, 0.f);
            if (j0 + r < 400)
                kv = *reinterpret_cast<const float4*>(qkv + base_k + (long)r * ld + c4 * 4);
            ushort4 h4;
            h4.x = f2bf(kv.x); h4.y = f2bf(kv.y); h4.z = f2bf(kv.z); h4.w = f2bf(kv.w);
            *reinterpret_cast<ushort4*>(&Ks[r][c4 * 4]) = h4;

            float4 av = make_float4(0.f, 0.f, 0.f, 0.f);
            if (i0 + r < 400 && j0 + c4 * 4 < 400)
                av = *reinterpret_cast<const float4*>(adj + ((long)b * 400 + i0 + r) * 400 + j0 + c4 * 4);
            ushort4 mb;
            mb.x = f2bf(av.x > 0.f ? 0.f : NEGBIG);
            mb.y = f2bf(av.y > 0.f ? 0.f : NEGBIG);
            mb.z = f2bf(av.z > 0.f ? 0.f : NEGBIG);
            mb.w = f2bf(av.w > 0.f ? 0.f : NEGBIG);
            *reinterpret_cast<ushort4*>(&Adjs[r][c4 * 4]) = mb;
        }
        {
            const int j4 = tid >> 4, d4 = tid & 15;
            float vv[4][4];
#pragma unroll
            for (int t = 0; t < 4; ++t) {
                float4 vl = make_float4(0.f, 0.f, 0.f, 0.f);
                if (j0 + j4 * 4 + t < 400)
                    vl = *reinterpret_cast<const float4*>(qkv + base_v + (long)(j4 * 4 + t) * ld + d4 * 4);
                vv[t][0] = vl.x; vv[t][1] = vl.y; vv[t][2] = vl.z; vv[t][3] = vl.w;
            }
#pragma unroll
            for (int u = 0; u < 4; ++u) {
                ushort4 h4;
                h4.x = f2bf(vv[0][u]); h4.y = f2bf(vv[1][u]);
                h4.z = f2bf(vv[2][u]); h4.w = f2bf(vv[3][u]);
                *reinterpret_cast<ushort4*>(&Vt[d4 * 4 + u][j4 * 4]) = h4;
            }
        }
        __syncthreads();

        f32x4 s4[4] = {};
#pragma unroll
        for (int ks = 0; ks < 2; ++ks) {
            const bf16x8 a = *reinterpret_cast<const bf16x8*>(&Qs[w * 16 + c][ks * 32 + g * 8]);
#pragma unroll
            for (int t = 0; t < 4; ++t) {
                const bf16x8 bb = *reinterpret_cast<const bf16x8*>(&Ks[t * 16 + c][ks * 32 + g * 8]);
                s4[t] = __builtin_amdgcn_mfma_f32_16x16x32_bf16(a, bb, s4[t], 0, 0, 0);
            }
        }

        float e[4][4];
        float pmax[4];
#pragma unroll
        for (int reg = 0; reg < 4; ++reg) {
            const int qr = w * 16 + g * 4 + reg;
            float mx = -3e38f;
#pragma unroll
            for (int t = 0; t < 4; ++t) {
                const float ev = s4[t][reg] * 0.125f + bf2f((unsigned short)Adjs[qr][t * 16 + c]);
                e[t][reg] = ev;
                mx = fmaxf(mx, ev);
            }
            pmax[reg] = mx;
        }
#pragma unroll
        for (int reg = 0; reg < 4; ++reg)
#pragma unroll
            for (int off = 1; off <= 8; off <<= 1)
                pmax[reg] = fmaxf(pmax[reg], __shfl_xor(pmax[reg], off, 64));

        float al[4];
#pragma unroll
        for (int reg = 0; reg < 4; ++reg) {
            const float mn = fmaxf(m[reg], pmax[reg]);
            al[reg] = __expf(m[reg] - mn);
            m[reg] = mn;
        }

#pragma unroll
        for (int reg = 0; reg < 4; ++reg) {
            const int qr = w * 16 + g * 4 + reg;
            float psum = 0.f;
#pragma unroll
            for (int t = 0; t < 4; ++t) {
                const float p = __expf(e[t][reg] - m[reg]);
                psum += p;
                Ps[qr][t * 16 + c] = (short)f2bf(p);
            }
            l[reg] = l[reg] * al[reg] + psum;
        }

#pragma unroll
        for (int dt = 0; dt < 4; ++dt)
#pragma unroll
            for (int reg = 0; reg < 4; ++reg)
                o[dt][reg] *= al[reg];

#pragma unroll
        for (int ks = 0; ks < 2; ++ks) {
            const bf16x8 a = *reinterpret_cast<const bf16x8*>(&Ps[w * 16 + c][ks * 32 + g * 8]);
#pragma unroll
            for (int dt = 0; dt < 4; ++dt) {
                const bf16x8 bb = *reinterpret_cast<const bf16x8*>(&Vt[dt * 16 + c][ks * 32 + g * 8]);
                o[dt] = __builtin_amdgcn_mfma_f32_16x16x32_bf16(a, bb, o[dt], 0, 0, 0);
            }
        }
    }

#pragma unroll
    for (int reg = 0; reg < 4; ++reg)
#pragma unroll
        for (int off = 1; off <= 8; off <<= 1)
            l[reg] += __shfl_xor(l[reg], off, 64);

#pragma unroll
    for (int reg = 0; reg < 4; ++reg) {
        const int gi = i0 + w * 16 + g * 4 + reg;
        if (gi < 400) {
            const float inv = 1.f / l[reg];
#pragma unroll
            for (int dt = 0; dt < 4; ++dt)
                ctx[((long)b * 400 + gi) * 256 + h * 64 + dt * 16 + c] = o[dt][reg] * inv;
        }
    }
}

// src[r] = h[r,:F].a[:F]; dst[r] = h[r,:F].a[F:2F]. One wave per row. h row stride ld.
__global__ __launch_bounds__(256) void gat_srcdst(
    const float* __restrict__ h, const float* __restrict__ a,
    float* __restrict__ src, float* __restrict__ dst, int F, int ld)
{
    const int row = blockIdx.x * 4 + (threadIdx.x >> 6);
    const int lane = threadIdx.x & 63;
    const float* hp = h + (long)row * ld;
    float s = 0.f, d = 0.f;
    for (int f = lane; f < F; f += 64) {
        const float hv = hp[f];
        s += hv * a[f];
        d += hv * a[F + f];
    }
    s = wave_sum(s);
    d = wave_sum(d);
    if (lane == 0) { src[row] = s; dst[row] = d; }
}

// attn[row,:] = softmax_j(mask(leaky_relu(src_i + dst_j, 0.2))). One wave per row.
__global__ __launch_bounds__(256) void gat_attn(
    const float* __restrict__ src, const float* __restrict__ dst,
    const float* __restrict__ adj, float* __restrict__ attn)
{
    const int row = blockIdx.x * 4 + (threadIdx.x >> 6);   // b*400+i
    const int b = row / 400;
    const int lane = threadIdx.x & 63;
    const float si = src[row];
    const float* db = dst + (long)b * 400;
    const float* adjrow = adj + (long)row * 400;

    float e[7];
    float mx = -3.0e38f;
#pragma unroll
    for (int t = 0; t < 7; ++t) {
        const int j = lane + 64 * t;
        float v = -3.0e38f;
        if (j < 400) {
            v = si + db[j];
            v = (v > 0.f) ? v : 0.2f * v;
            if (!(adjrow[j] > 0.f)) v = NEGBIG;
        }
        e[t] = v;
        mx = fmaxf(mx, v);
    }
    mx = wave_max(mx);

    float p[7];
    float sum = 0.f;
#pragma unroll
    for (int t = 0; t < 7; ++t) {
        const int j = lane + 64 * t;
        if (j < 400) {
            p[t] = __expf(e[t] - mx);
            sum += p[t];
        }
    }
    sum = wave_sum(sum);
    const float inv = 1.f / sum;
#pragma unroll
    for (int t = 0; t < 7; ++t) {
        const int j = lane + 64 * t;
        if (j < 400) attn[(long)row * 400 + j] = p[t] * inv;
    }
}

// LayerNorm over last dim F (+optional ELU). One wave per row. in row stride ldIn.
template<int F, bool ELU>
__global__ __launch_bounds__(256) void ln_kernel(
    const float* __restrict__ in, int ldIn, const float* __restrict__ g,
    const float* __restrict__ b, float* __restrict__ out)
{
    const int row = blockIdx.x * 4 + (threadIdx.x >> 6);
    const int lane = threadIdx.x & 63;
    constexpr int PER = F / 64;
    const float* ip = in + (long)row * ldIn;

    float v[PER];
    float s = 0.f;
#pragma unroll
    for (int t = 0; t < PER; ++t) {
        v[t] = ip[lane + 64 * t];
        s += v[t];
    }
    s = wave_sum(s);
    const float mean = s * (1.f / F);
    float vs = 0.f;
#pragma unroll
    for (int t = 0; t < PER; ++t) {
        const float d = v[t] - mean;
        vs += d * d;
    }
    vs = wave_sum(vs);
    const float rstd = rsqrtf(vs * (1.f / F) + 1e-5f);
#pragma unroll
    for (int t = 0; t < PER; ++t) {
        const int col = lane + 64 * t;
        float y = (v[t] - mean) * rstd * g[col] + b[col];
        if (ELU) y = (y > 0.f) ? y : expm1f(y);
        out[(long)row * F + col] = y;
    }
}

extern "C" void kernel_launch(void* const* d_in, const int* in_sizes, int n_in,
                              void* d_out, int out_size, void* d_ws, size_t ws_size,
                              hipStream_t stream) {
    const float* x    = (const float*)d_in[0];
    const float* adj  = (const float*)d_in[1];
    const float* Wq   = (const float*)d_in[2];
    const float* bq   = (const float*)d_in[3];
    const float* Wk   = (const float*)d_in[4];
    const float* bk   = (const float*)d_in[5];
    const float* Wv   = (const float*)d_in[6];
    const float* bv   = (const float*)d_in[7];
    const float* Wo   = (const float*)d_in[8];
    const float* bo   = (const float*)d_in[9];
    const float* g1W  = (const float*)d_in[10];
    const float* g1a  = (const float*)d_in[11];
    const float* g2W  = (const float*)d_in[12];
    const float* g2a  = (const float*)d_in[13];
    const float* g3W  = (const float*)d_in[14];
    const float* g3a  = (const float*)d_in[15];
    const float* r1W  = (const float*)d_in[16];
    const float* r1b  = (const float*)d_in[17];
    const float* r2W  = (const float*)d_in[18];
    const float* r2b  = (const float*)d_in[19];
    const float* r3W  = (const float*)d_in[20];
    const float* r3b  = (const float*)d_in[21];
    const float* ln1g = (const float*)d_in[22];
    const float* ln1b = (const float*)d_in[23];
    const float* ln2g = (const float*)d_in[24];
    const float* ln2b = (const float*)d_in[25];
    const float* ln3g = (const float*)d_in[26];
    const float* ln3b = (const float*)d_in[27];

    float* out_x = (float*)d_out;              // [25600,128]
    float* attn1 = out_x + 3276800;            // [64,400,400]
    float* attn2 = attn1 + 10240000;
    float* attn3 = attn2 + 10240000;

    float* bufA = (float*)d_ws;                // 6553600 f32 each
    float* bufB = bufA + 6553600;
    float* bufC = bufB + 6553600;
    float* bufD = bufC + 6553600;
    float* srcb = bufD + 6553600;              // [25600]
    float* dstb = srcb + 25600;                // [25600]
    unsigned short* wT   = (unsigned short*)(dstb + 25600);
    unsigned short* wTq  = wT;                 // [256][400]  (qkv block: contiguous 768 rows)
    unsigned short* wTk  = wT + 102400;
    unsigned short* wTv  = wT + 204800;
    unsigned short* wTo  = wT + 307200;        // [400][256]
    unsigned short* wTg1 = wT + 409600;        // [256][400]  (g1r1 block: 512 rows)
    unsigned short* wTr1 = wT + 512000;
    unsigned short* wTg2 = wT + 614400;        // [256][256]  (g2r2 block: 512 rows)
    unsigned short* wTr2 = wT + 679936;
    unsigned short* wTg3 = wT + 745472;        // [128][256]  (g3r3 block: 256 rows)
    unsigned short* wTr3 = wT + 778240;
    float* bias0 = (float*)(wT + 811008);
    float* bqkv = bias0;                       // [768]
    float* bgr1 = bqkv + 768;                  // [512]
    float* bgr2 = bgr1 + 512;                  // [512]
    float* bgr3 = bgr2 + 512;                  // [256]

    // aliases
    float* qkv = bufA;                         // [25600][768] (spans A,B,C)
    float* ctx = bufD;                         // [25600][256]
    float* xc  = attn1;                        // [25600][400] (dead until gat_attn writes attn1)
    float* hr1 = bufA;                         // [25600][512]: h1 cols 0-255, res1 cols 256-511
    float* hr3 = bufA;                         // [25600][256]: h3 cols 0-127, res3 cols 128-255
    unsigned short* hT = (unsigned short*)bufD;  // per-layer h^T bf16 [64][F][400]
    float* x2 = bufC;
    float* x3 = bufC;

    const dim3 b256(256), b512(512);
    const int M = 25600;

    // ---- Phase 0: weight transposes + biases ----
    build_biases<<<1, b256, 0, stream>>>(bqkv, bq, bk, bv, bgr1, r1b, bgr2, r2b, bgr3, r3b);
    transpose_to_bf16<<<dim3(8, 13), b256, 0, stream>>>(Wq,  wTq, 400, 256, 256, 0, 0);
    transpose_to_bf16<<<dim3(8, 13), b256, 0, stream>>>(Wk,  wTk, 400, 256, 256, 0, 0);
    transpose_to_bf16<<<dim3(8, 13), b256, 0, stream>>>(Wv,  wTv, 400, 256, 256, 0, 0);
    transpose_to_bf16<<<dim3(13, 8), b256, 0, stream>>>(Wo,  wTo, 256, 400, 400, 0, 0);
    transpose_to_bf16<<<dim3(8, 13), b256, 0, stream>>>(g1W, wTg1, 400, 256, 256, 0, 0);
    transpose_to_bf16<<<dim3(8, 13), b256, 0, stream>>>(r1W, wTr1, 400, 256, 256, 0, 0);
    transpose_to_bf16<<<dim3(8, 8),  b256, 0, stream>>>(g2W, wTg2, 256, 256, 256, 0, 0);
    transpose_to_bf16<<<dim3(8, 8),  b256, 0, stream>>>(r2W, wTr2, 256, 256, 256, 0, 0);
    transpose_to_bf16<<<dim3(4, 8),  b256, 0, stream>>>(g3W, wTg3, 256, 128, 128, 0, 0);
    transpose_to_bf16<<<dim3(4, 8),  b256, 0, stream>>>(r3W, wTr3, 256, 128, 128, 0, 0);

    // ---- Phase 1: MHA ----
    // qkv = x @ [Wq|Wk|Wv] + [bq|bk|bv]
    gemm_mfma<true, false, false><<<dim3(3, 200), b512, 0, stream>>>(
        x, wTq, bqkv, nullptr, qkv, M, 400, 768, 400, 768, 0, 0, 0);
    mha_flash_mfma<<<dim3(7, 4, 64), b256, 0, stream>>>(qkv, adj, ctx, 768);
    gemm_mfma<true, false, true><<<dim3(2, 200), b512, 0, stream>>>(
        ctx, wTo, bo, x, xc, M, 256, 400, 256, 400, 0, 0, 0);

    // ---- Phase 2: GAT1 (400 -> 256) ----
    gemm_mfma<true, false, false><<<dim3(2, 200), b512, 0, stream>>>(
        xc, wTg1, bgr1, nullptr, hr1, M, 400, 512, 400, 512, 0, 0, 0);
    gat_srcdst<<<dim3(6400), b256, 0, stream>>>(hr1, g1a, srcb, dstb, 256, 512);
    gat_attn<<<dim3(6400), b256, 0, stream>>>(srcb, dstb, adj, attn1);   // xc dead
    transpose_to_bf16<<<dim3(8, 13, 64), b256, 0, stream>>>(hr1, hT, 400, 256, 512, 204800, 102400);
    gemm_mfma<false, true, false><<<dim3(1, 4, 64), b512, 0, stream>>>(
        attn1, hT, nullptr, nullptr, hr1 + 256, 400, 400, 256, 400, 512, 160000, 102400, 204800);
    ln_kernel<256, true><<<dim3(6400), b256, 0, stream>>>(hr1 + 256, 512, ln1g, ln1b, x2);

    // ---- Phase 3: GAT2 (256 -> 256) ----
    gemm_mfma<true, false, false><<<dim3(2, 200), b512, 0, stream>>>(
        x2, wTg2, bgr2, nullptr, hr1, M, 256, 512, 256, 512, 0, 0, 0);
    gat_srcdst<<<dim3(6400), b256, 0, stream>>>(hr1, g2a, srcb, dstb, 256, 512);
    gat_attn<<<dim3(6400), b256, 0, stream>>>(srcb, dstb, adj, attn2);
    transpose_to_bf16<<<dim3(8, 13, 64), b256, 0, stream>>>(hr1, hT, 400, 256, 512, 204800, 102400);
    gemm_mfma<false, true, false><<<dim3(1, 4, 64), b512, 0, stream>>>(
        attn2, hT, nullptr, nullptr, hr1 + 256, 400, 400, 256, 400, 512, 160000, 102400, 204800);
    ln_kernel<256, true><<<dim3(6400), b256, 0, stream>>>(hr1 + 256, 512, ln2g, ln2b, x3);

    // ---- Phase 4: GAT3 (256 -> 128) ----
    gemm_mfma<true, false, false><<<dim3(1, 200), b512, 0, stream>>>(
        x3, wTg3, bgr3, nullptr, hr3, M, 256, 256, 256, 256, 0, 0, 0);
    gat_srcdst<<<dim3(6400), b256, 0, stream>>>(hr3, g3a, srcb, dstb, 128, 256);
    gat_attn<<<dim3(6400), b256, 0, stream>>>(srcb, dstb, adj, attn3);
    transpose_to_bf16<<<dim3(4, 13, 64), b256, 0, stream>>>(hr3, hT, 400, 128, 256, 102400, 51200);
    gemm_mfma<false, true, false><<<dim3(1, 4, 64), b512, 0, stream>>>(
        attn3, hT, nullptr, nullptr, hr3 + 128, 400, 400, 128, 400, 256, 160000, 51200, 102400);
    ln_kernel<128, false><<<dim3(6400), b256, 0, stream>>>(hr3 + 128, 256, ln3g, ln3b, out_x);
}

// Round 10
// 760.596 us; speedup vs baseline: 4.3724x; 1.1206x over previous
//
#include <hip/hip_runtime.h>

// GraphEncoder: MHA + 3×(GAT + residual-proj + LN[+ELU]).
// B=64, N=400, D=400, Hd=256, E=128, H=4, hd=64.
// bf16 dataflow: activations consumed only by MFMA are stored bf16 once.
// d_out layout (f32): x_final [64*400*128] | attn1 [64*400*400] | attn2 | attn3

#define NEGBIG (-1e9f)

typedef __attribute__((ext_vector_type(8))) short bf16x8;
typedef __attribute__((ext_vector_type(4))) float f32x4;

__device__ inline unsigned short f2bf(float f) {
    unsigned u = __builtin_bit_cast(unsigned, f);
    u += 0x7fffu + ((u >> 16) & 1u);          // RNE
    return (unsigned short)(u >> 16);
}
__device__ inline float bf2f(unsigned short h) {
    unsigned u = ((unsigned)h) << 16;
    return __builtin_bit_cast(float, u);
}

__device__ inline float wave_sum(float v) {
#pragma unroll
    for (int off = 32; off >= 1; off >>= 1)
        v += __shfl_xor(v, off, 64);
    return v;
}
__device__ inline float wave_max(float v) {
#pragma unroll
    for (int off = 32; off >= 1; off >>= 1)
        v = fmaxf(v, __shfl_xor(v, off, 64));
    return v;
}

// ---------------------------------------------------------------------------
__global__ void build_biases(
    float* bqkv, const float* bq, const float* bk, const float* bv,
    float* bgr1, const float* r1b, float* bgr2, const float* r2b,
    float* bgr3, const float* r3b)
{
    const int t = threadIdx.x;
    bqkv[t] = bq[t]; bqkv[256 + t] = bk[t]; bqkv[512 + t] = bv[t];
    bgr1[t] = 0.f; bgr1[256 + t] = r1b[t];
    bgr2[t] = 0.f; bgr2[256 + t] = r2b[t];
    if (t < 128) { bgr3[t] = 0.f; bgr3[128 + t] = r3b[t]; }
}

// adj f32 -> additive maskbias bf16 (0 where edge, -1e9 where none)
__global__ __launch_bounds__(256) void adj2mask(
    const float* __restrict__ adj, unsigned short* __restrict__ mb)
{
    const long i = ((long)blockIdx.x * 256 + threadIdx.x) * 4;
    const float4 a = *reinterpret_cast<const float4*>(adj + i);
    ushort4 o;
    o.x = f2bf(a.x > 0.f ? 0.f : NEGBIG);
    o.y = f2bf(a.y > 0.f ? 0.f : NEGBIG);
    o.z = f2bf(a.z > 0.f ? 0.f : NEGBIG);
    o.w = f2bf(a.w > 0.f ? 0.f : NEGBIG);
    *reinterpret_cast<ushort4*>(mb + i) = o;
}

// ---------------------------------------------------------------------------
// Transpose + f32->bf16: out[c][r] = bf16(in[r][c]). in rows R cols C stride ldIn.
__global__ __launch_bounds__(256) void transpose_to_bf16(
    const float* __restrict__ in, unsigned short* __restrict__ out,
    int R, int C, int ldIn, long sIn, long sOut)
{
    in  += (long)blockIdx.z * sIn;
    out += (long)blockIdx.z * sOut;
    __shared__ float t[32][33];
    const int r0 = blockIdx.y * 32, c0 = blockIdx.x * 32;
    const int tid = threadIdx.x;

    const int row = tid >> 3, c4 = tid & 7;
    float4 v = make_float4(0.f, 0.f, 0.f, 0.f);
    if (r0 + row < R && c0 + c4 * 4 < C)
        v = *reinterpret_cast<const float4*>(&in[(long)(r0 + row) * ldIn + c0 + c4 * 4]);
    t[row][c4 * 4 + 0] = v.x;
    t[row][c4 * 4 + 1] = v.y;
    t[row][c4 * 4 + 2] = v.z;
    t[row][c4 * 4 + 3] = v.w;
    __syncthreads();

    const int oc = tid >> 3, r4 = tid & 7;
    if (c0 + oc < C && r0 + r4 * 4 < R) {
        ushort4 o;
        o.x = f2bf(t[r4 * 4 + 0][oc]);
        o.y = f2bf(t[r4 * 4 + 1][oc]);
        o.z = f2bf(t[r4 * 4 + 2][oc]);
        o.w = f2bf(t[r4 * 4 + 3][oc]);
        *reinterpret_cast<ushort4*>(&out[(long)(c0 + oc) * R + r0 + r4 * 4]) = o;
    }
}

// ---------------------------------------------------------------------------
// C[M,Nc] = A[M,K] @ BT[Nc,K](bf16)  (+bias)(+resid f32)(+=C)
// A f32 (converted) or bf16 (ABHALF). C f32 or bf16 (OUTBF16).
// Tile 128x256x32, 512 threads = 8 waves (2x4), wave 64x64, mfma 16x16x32.
template<bool BIAS, bool ACCUM, bool RESID, bool ABHALF, bool OUTBF16>
__global__ __launch_bounds__(512) void gemm_mfma(
    const void* __restrict__ Av, const unsigned short* __restrict__ BT,
    const float* __restrict__ bias, const float* __restrict__ resid,
    void* __restrict__ Cv, int M, int K, int Nc, int ldA, int ldC,
    long sA, long sBT, long sC)
{
    const int bz = blockIdx.z;
    const float* Af = ABHALF ? nullptr : ((const float*)Av + (long)bz * sA);
    const unsigned short* Ah = ABHALF ? ((const unsigned short*)Av + (long)bz * sA) : nullptr;
    BT += (long)bz * sBT;
    float* Cf = OUTBF16 ? nullptr : ((float*)Cv + (long)bz * sC);
    unsigned short* Ch = OUTBF16 ? ((unsigned short*)Cv + (long)bz * sC) : nullptr;
    const float* Rp = RESID ? (resid + (long)bz * sC) : nullptr;

    __shared__ short As[128][40];
    __shared__ short Bs[256][40];

    const int tid = threadIdx.x;
    const int lane = tid & 63, wave = tid >> 6;
    const int wm = wave >> 2, wn = wave & 3;
    const int m0 = blockIdx.y * 128, n0 = blockIdx.x * 256;

    f32x4 acc[4][4] = {};

    const int nk = (K + 31) / 32;
    for (int kt = 0; kt < nk; ++kt) {
        const int k0 = kt * 32;
        __syncthreads();
        if (ABHALF) {
            const int row = tid >> 2, k8 = tid & 3;
            const int gm = m0 + row, gk = k0 + k8 * 8;
            uint4 av = make_uint4(0u, 0u, 0u, 0u);
            if (gm < M && gk < K)
                av = *reinterpret_cast<const uint4*>(&Ah[(long)gm * ldA + gk]);
            *reinterpret_cast<uint4*>(&As[row][k8 * 8]) = av;
        } else {
#pragma unroll
            for (int p = 0; p < 2; ++p) {
                const int idx = tid + p * 512;
                const int row = idx >> 3, k4 = idx & 7;
                const int gm = m0 + row, gk = k0 + k4 * 4;
                float4 av = make_float4(0.f, 0.f, 0.f, 0.f);
                if (gm < M && gk < K)
                    av = *reinterpret_cast<const float4*>(&Af[(long)gm * ldA + gk]);
                ushort4 h4;
                h4.x = f2bf(av.x); h4.y = f2bf(av.y); h4.z = f2bf(av.z); h4.w = f2bf(av.w);
                *reinterpret_cast<ushort4*>(&As[row][k4 * 4]) = h4;
            }
        }
#pragma unroll
        for (int p = 0; p < 2; ++p) {
            const int idx = tid + p * 512;
            const int n = idx >> 2, k8 = idx & 3;
            const int gn = n0 + n, gk = k0 + k8 * 8;
            uint4 bv = make_uint4(0u, 0u, 0u, 0u);
            if (gn < Nc && gk < K)
                bv = *reinterpret_cast<const uint4*>(&BT[(long)gn * K + gk]);
            *reinterpret_cast<uint4*>(&Bs[n][k8 * 8]) = bv;
        }
        __syncthreads();

        const int fr = lane & 15, fkb = (lane >> 4) * 8;
        bf16x8 a[4], b[4];
#pragma unroll
        for (int i = 0; i < 4; ++i)
            a[i] = *reinterpret_cast<const bf16x8*>(&As[wm * 64 + i * 16 + fr][fkb]);
#pragma unroll
        for (int j = 0; j < 4; ++j)
            b[j] = *reinterpret_cast<const bf16x8*>(&Bs[wn * 64 + j * 16 + fr][fkb]);
#pragma unroll
        for (int i = 0; i < 4; ++i)
#pragma unroll
            for (int j = 0; j < 4; ++j)
                acc[i][j] = __builtin_amdgcn_mfma_f32_16x16x32_bf16(a[i], b[j], acc[i][j], 0, 0, 0);
    }

    const int fr = lane & 15, rg = lane >> 4;
#pragma unroll
    for (int i = 0; i < 4; ++i) {
#pragma unroll
        for (int j = 0; j < 4; ++j) {
#pragma unroll
            for (int r = 0; r < 4; ++r) {
                const int gm = m0 + wm * 64 + i * 16 + rg * 4 + r;
                const int gn = n0 + wn * 64 + j * 16 + fr;
                if (gm < M && gn < Nc) {
                    float v = acc[i][j][r];
                    if (BIAS)  v += bias[gn];
                    if (RESID) v += Rp[(long)gm * ldC + gn];
                    if (OUTBF16) {
                        Ch[(long)gm * ldC + gn] = f2bf(v);
                    } else {
                        if (ACCUM) v += Cf[(long)gm * ldC + gn];
                        Cf[(long)gm * ldC + gn] = v;
                    }
                }
            }
        }
    }
}

// ---------------------------------------------------------------------------
// Flash MHA on MFMA, bf16 in/out. qkv bf16 [25600][768]; mask bf16 additive.
// Grid (7 q-tiles, 4 heads, 64 batches), 4 waves; wave w owns q-rows w*16..+15.
__global__ __launch_bounds__(256) void mha_flash_mfma(
    const unsigned short* __restrict__ qkv, const unsigned short* __restrict__ mask,
    unsigned short* __restrict__ ctx, int ld)
{
    const int it = blockIdx.x, h = blockIdx.y, b = blockIdx.z;
    const int i0 = it * 64;
    const int tid = threadIdx.x;
    const int lane = tid & 63, w = tid >> 6;
    const int c = lane & 15, g = lane >> 4;
    const unsigned short NEGBF = f2bf(NEGBIG);

    __shared__ short Qs[64][72];    // [qrow][d]
    __shared__ short Ks[64][72];    // [jrow][d]
    __shared__ short Vt[64][72];    // [d][jrow]
    __shared__ short Ps[64][72];    // [qrow][jrow] wave-private bands
    __shared__ short Adjs[64][72];  // maskbias tile

    const long base_q = ((long)b * 400 + i0) * ld + h * 64;
#pragma unroll
    for (int p = 0; p < 2; ++p) {
        const int idx = tid + p * 256;
        const int r = idx >> 3, c8 = idx & 7;
        uint4 qv = make_uint4(0u, 0u, 0u, 0u);
        if (i0 + r < 400)
            qv = *reinterpret_cast<const uint4*>(qkv + base_q + (long)r * ld + c8 * 8);
        *reinterpret_cast<uint4*>(&Qs[r][c8 * 8]) = qv;
    }

    f32x4 o[4] = {};
    float m[4] = {-3e38f, -3e38f, -3e38f, -3e38f};
    float l[4] = {0.f, 0.f, 0.f, 0.f};

    for (int jt = 0; jt < 7; ++jt) {
        const int j0 = jt * 64;
        __syncthreads();

        const long base_k = ((long)b * 400 + j0) * ld + 256 + h * 64;
        const long base_v = base_k + 256;
        // K rows + maskbias rows
#pragma unroll
        for (int p = 0; p < 2; ++p) {
            const int idx = tid + p * 256;
            const int r = idx >> 3, c8 = idx & 7;
            uint4 kv = make_uint4(0u, 0u, 0u, 0u);
            if (j0 + r < 400)
                kv = *reinterpret_cast<const uint4*>(qkv + base_k + (long)r * ld + c8 * 8);
            *reinterpret_cast<uint4*>(&Ks[r][c8 * 8]) = kv;

            ushort4 mb = make_ushort4(NEGBF, NEGBF, NEGBF, NEGBF);
            ushort4 mb2 = mb;
            if (i0 + r < 400 && j0 + c8 * 8 + 7 < 400) {
                const uint4 mv = *reinterpret_cast<const uint4*>(
                    mask + ((long)b * 400 + i0 + r) * 400 + j0 + c8 * 8);
                mb  = *reinterpret_cast<const ushort4*>(&mv.x);
                mb2 = *reinterpret_cast<const ushort4*>(&mv.z);
            }
            *reinterpret_cast<ushort4*>(&Adjs[r][c8 * 8]) = mb;
            *reinterpret_cast<ushort4*>(&Adjs[r][c8 * 8 + 4]) = mb2;
        }
        // V transpose staging (bf16 4x4 blocks)
        {
            const int j4 = tid >> 4, d4 = tid & 15;
            ushort4 vl[4];
#pragma unroll
            for (int t = 0; t < 4; ++t) {
                vl[t] = make_ushort4(0, 0, 0, 0);
                if (j0 + j4 * 4 + t < 400)
                    vl[t] = *reinterpret_cast<const ushort4*>(qkv + base_v + (long)(j4 * 4 + t) * ld + d4 * 4);
            }
#pragma unroll
            for (int u = 0; u < 4; ++u) {
                ushort4 h4;
                h4.x = ((const unsigned short*)&vl[0])[u];
                h4.y = ((const unsigned short*)&vl[1])[u];
                h4.z = ((const unsigned short*)&vl[2])[u];
                h4.w = ((const unsigned short*)&vl[3])[u];
                *reinterpret_cast<ushort4*>(&Vt[d4 * 4 + u][j4 * 4]) = h4;
            }
        }
        __syncthreads();

        f32x4 s4[4] = {};
#pragma unroll
        for (int ks = 0; ks < 2; ++ks) {
            const bf16x8 a = *reinterpret_cast<const bf16x8*>(&Qs[w * 16 + c][ks * 32 + g * 8]);
#pragma unroll
            for (int t = 0; t < 4; ++t) {
                const bf16x8 bb = *reinterpret_cast<const bf16x8*>(&Ks[t * 16 + c][ks * 32 + g * 8]);
                s4[t] = __builtin_amdgcn_mfma_f32_16x16x32_bf16(a, bb, s4[t], 0, 0, 0);
            }
        }

        float e[4][4];
        float pmax[4];
#pragma unroll
        for (int reg = 0; reg < 4; ++reg) {
            const int qr = w * 16 + g * 4 + reg;
            float mx = -3e38f;
#pragma unroll
            for (int t = 0; t < 4; ++t) {
                const float ev = s4[t][reg] * 0.125f + bf2f((unsigned short)Adjs[qr][t * 16 + c]);
                e[t][reg] = ev;
                mx = fmaxf(mx, ev);
            }
            pmax[reg] = mx;
        }
#pragma unroll
        for (int reg = 0; reg < 4; ++reg)
#pragma unroll
            for (int off = 1; off <= 8; off <<= 1)
                pmax[reg] = fmaxf(pmax[reg], __shfl_xor(pmax[reg], off, 64));

        float al[4];
#pragma unroll
        for (int reg = 0; reg < 4; ++reg) {
            const float mn = fmaxf(m[reg], pmax[reg]);
            al[reg] = __expf(m[reg] - mn);
            m[reg] = mn;
        }

#pragma unroll
        for (int reg = 0; reg < 4; ++reg) {
            const int qr = w * 16 + g * 4 + reg;
            float psum = 0.f;
#pragma unroll
            for (int t = 0; t < 4; ++t) {
                const float p = __expf(e[t][reg] - m[reg]);
                psum += p;
                Ps[qr][t * 16 + c] = (short)f2bf(p);
            }
            l[reg] = l[reg] * al[reg] + psum;
        }

#pragma unroll
        for (int dt = 0; dt < 4; ++dt)
#pragma unroll
            for (int reg = 0; reg < 4; ++reg)
                o[dt][reg] *= al[reg];

#pragma unroll
        for (int ks = 0; ks < 2; ++ks) {
            const bf16x8 a = *reinterpret_cast<const bf16x8*>(&Ps[w * 16 + c][ks * 32 + g * 8]);
#pragma unroll
            for (int dt = 0; dt < 4; ++dt) {
                const bf16x8 bb = *reinterpret_cast<const bf16x8*>(&Vt[dt * 16 + c][ks * 32 + g * 8]);
                o[dt] = __builtin_amdgcn_mfma_f32_16x16x32_bf16(a, bb, o[dt], 0, 0, 0);
            }
        }
    }

#pragma unroll
    for (int reg = 0; reg < 4; ++reg)
#pragma unroll
        for (int off = 1; off <= 8; off <<= 1)
            l[reg] += __shfl_xor(l[reg], off, 64);

#pragma unroll
    for (int reg = 0; reg < 4; ++reg) {
        const int gi = i0 + w * 16 + g * 4 + reg;
        if (gi < 400) {
            const float inv = 1.f / l[reg];
#pragma unroll
            for (int dt = 0; dt < 4; ++dt)
                ctx[((long)b * 400 + gi) * 256 + h * 64 + dt * 16 + c] = f2bf(o[dt][reg] * inv);
        }
    }
}

// src/dst projections. h f32 row stride ld.
__global__ __launch_bounds__(256) void gat_srcdst(
    const float* __restrict__ h, const float* __restrict__ a,
    float* __restrict__ src, float* __restrict__ dst, int F, int ld)
{
    const int row = blockIdx.x * 4 + (threadIdx.x >> 6);
    const int lane = threadIdx.x & 63;
    const float* hp = h + (long)row * ld;
    float s = 0.f, d = 0.f;
    for (int f = lane; f < F; f += 64) {
        const float hv = hp[f];
        s += hv * a[f];
        d += hv * a[F + f];
    }
    s = wave_sum(s);
    d = wave_sum(d);
    if (lane == 0) { src[row] = s; dst[row] = d; }
}

// attn row softmax; writes f32 (d_out) + bf16 side copy (ws).
__global__ __launch_bounds__(256) void gat_attn(
    const float* __restrict__ src, const float* __restrict__ dst,
    const unsigned short* __restrict__ mask,
    float* __restrict__ attn, unsigned short* __restrict__ attnb)
{
    const int row = blockIdx.x * 4 + (threadIdx.x >> 6);   // b*400+i
    const int b = row / 400;
    const int lane = threadIdx.x & 63;
    const float si = src[row];
    const float* db = dst + (long)b * 400;
    const unsigned short* mrow = mask + (long)row * 400;

    float e[7];
    float mx = -3.0e38f;
#pragma unroll
    for (int t = 0; t < 7; ++t) {
        const int j = lane + 64 * t;
        float v = -3.0e38f;
        if (j < 400) {
            v = si + db[j];
            v = (v > 0.f) ? v : 0.2f * v;
            v += bf2f(mrow[j]);
        }
        e[t] = v;
        mx = fmaxf(mx, v);
    }
    mx = wave_max(mx);

    float p[7];
    float sum = 0.f;
#pragma unroll
    for (int t = 0; t < 7; ++t) {
        const int j = lane + 64 * t;
        if (j < 400) {
            p[t] = __expf(e[t] - mx);
            sum += p[t];
        }
    }
    sum = wave_sum(sum);
    const float inv = 1.f / sum;
#pragma unroll
    for (int t = 0; t < 7; ++t) {
        const int j = lane + 64 * t;
        if (j < 400) {
            const float pv = p[t] * inv;
            attn[(long)row * 400 + j] = pv;
            attnb[(long)row * 400 + j] = f2bf(pv);
        }
    }
}

// LayerNorm (+ELU) — out f32 or bf16.
template<int F, bool ELU, bool OB16>
__global__ __launch_bounds__(256) void ln_kernel(
    const float* __restrict__ in, int ldIn, const float* __restrict__ g,
    const float* __restrict__ b, void* __restrict__ outv)
{
    const int row = blockIdx.x * 4 + (threadIdx.x >> 6);
    const int lane = threadIdx.x & 63;
    constexpr int PER = F / 64;
    const float* ip = in + (long)row * ldIn;

    float v[PER];
    float s = 0.f;
#pragma unroll
    for (int t = 0; t < PER; ++t) {
        v[t] = ip[lane + 64 * t];
        s += v[t];
    }
    s = wave_sum(s);
    const float mean = s * (1.f / F);
    float vs = 0.f;
#pragma unroll
    for (int t = 0; t < PER; ++t) {
        const float d = v[t] - mean;
        vs += d * d;
    }
    vs = wave_sum(vs);
    const float rstd = rsqrtf(vs * (1.f / F) + 1e-5f);
#pragma unroll
    for (int t = 0; t < PER; ++t) {
        const int col = lane + 64 * t;
        float y = (v[t] - mean) * rstd * g[col] + b[col];
        if (ELU) y = (y > 0.f) ? y : expm1f(y);
        if (OB16) ((unsigned short*)outv)[(long)row * F + col] = f2bf(y);
        else      ((float*)outv)[(long)row * F + col] = y;
    }
}

extern "C" void kernel_launch(void* const* d_in, const int* in_sizes, int n_in,
                              void* d_out, int out_size, void* d_ws, size_t ws_size,
                              hipStream_t stream) {
    const float* x    = (const float*)d_in[0];
    const float* adj  = (const float*)d_in[1];
    const float* Wq   = (const float*)d_in[2];
    const float* bq   = (const float*)d_in[3];
    const float* Wk   = (const float*)d_in[4];
    const float* bk   = (const float*)d_in[5];
    const float* Wv   = (const float*)d_in[6];
    const float* bv   = (const float*)d_in[7];
    const float* Wo   = (const float*)d_in[8];
    const float* bo   = (const float*)d_in[9];
    const float* g1W  = (const float*)d_in[10];
    const float* g1a  = (const float*)d_in[11];
    const float* g2W  = (const float*)d_in[12];
    const float* g2a  = (const float*)d_in[13];
    const float* g3W  = (const float*)d_in[14];
    const float* g3a  = (const float*)d_in[15];
    const float* r1W  = (const float*)d_in[16];
    const float* r1b  = (const float*)d_in[17];
    const float* r2W  = (const float*)d_in[18];
    const float* r2b  = (const float*)d_in[19];
    const float* r3W  = (const float*)d_in[20];
    const float* r3b  = (const float*)d_in[21];
    const float* ln1g = (const float*)d_in[22];
    const float* ln1b = (const float*)d_in[23];
    const float* ln2g = (const float*)d_in[24];
    const float* ln2b = (const float*)d_in[25];
    const float* ln3g = (const float*)d_in[26];
    const float* ln3b = (const float*)d_in[27];

    float* out_x = (float*)d_out;              // [25600,128]
    float* attn1 = out_x + 3276800;            // [64,400,400]
    float* attn2 = attn1 + 10240000;
    float* attn3 = attn2 + 10240000;

    char* wsb = (char*)d_ws;
    // R1 [0, 52.4MB): hr f32 [25600][512]; early alias: ctx bf16 [25600][256]
    float*          hrF  = (float*)wsb;
    unsigned short* ctxH = (unsigned short*)wsb;
    // R2 [52.4, 91.8MB): qkv bf16 [25600][768]; later: attn bf16 + hT + x2/x3
    unsigned short* qkvH  = (unsigned short*)(wsb + 52428800);
    unsigned short* attnH = qkvH;                              // [64][400][400]
    unsigned short* x2H   = qkvH;                              // [25600][256] (ln->gemm window)
    unsigned short* hT    = (unsigned short*)(wsb + 72908800); // [64][256][400]
    // R3 [91.8, 112.2MB): maskbias bf16 [64][400][400]
    unsigned short* maskH = (unsigned short*)(wsb + 91750400);
    // R4: small
    float* srcb = (float*)(wsb + 112230400);   // [25600]
    float* dstb = (float*)(wsb + 112332800);   // [25600]
    unsigned short* wT = (unsigned short*)(wsb + 112435200);
    unsigned short* wTq  = wT;                 // [256][400]
    unsigned short* wTk  = wT + 102400;
    unsigned short* wTv  = wT + 204800;
    unsigned short* wTo  = wT + 307200;        // [400][256]
    unsigned short* wTg1 = wT + 409600;        // [256][400]
    unsigned short* wTr1 = wT + 512000;
    unsigned short* wTg2 = wT + 614400;        // [256][256]
    unsigned short* wTr2 = wT + 679936;
    unsigned short* wTg3 = wT + 745472;        // [128][256]
    unsigned short* wTr3 = wT + 778240;
    float* bqkv = (float*)(wsb + 114057216);   // [768]
    float* bgr1 = bqkv + 768;                  // [512]
    float* bgr2 = bgr1 + 512;                  // [512]
    float* bgr3 = bgr2 + 512;                  // [256]
    unsigned short* xcH = (unsigned short*)attn1;   // xc bf16 in attn1 region (dead before gat_attn1)

    const dim3 b256(256), b512(512);
    const int M = 25600;

    // ---- Phase 0 ----
    build_biases<<<1, b256, 0, stream>>>(bqkv, bq, bk, bv, bgr1, r1b, bgr2, r2b, bgr3, r3b);
    adj2mask<<<dim3(10000), b256, 0, stream>>>(adj, maskH);
    transpose_to_bf16<<<dim3(8, 13), b256, 0, stream>>>(Wq,  wTq, 400, 256, 256, 0, 0);
    transpose_to_bf16<<<dim3(8, 13), b256, 0, stream>>>(Wk,  wTk, 400, 256, 256, 0, 0);
    transpose_to_bf16<<<dim3(8, 13), b256, 0, stream>>>(Wv,  wTv, 400, 256, 256, 0, 0);
    transpose_to_bf16<<<dim3(13, 8), b256, 0, stream>>>(Wo,  wTo, 256, 400, 400, 0, 0);
    transpose_to_bf16<<<dim3(8, 13), b256, 0, stream>>>(g1W, wTg1, 400, 256, 256, 0, 0);
    transpose_to_bf16<<<dim3(8, 13), b256, 0, stream>>>(r1W, wTr1, 400, 256, 256, 0, 0);
    transpose_to_bf16<<<dim3(8, 8),  b256, 0, stream>>>(g2W, wTg2, 256, 256, 256, 0, 0);
    transpose_to_bf16<<<dim3(8, 8),  b256, 0, stream>>>(r2W, wTr2, 256, 256, 256, 0, 0);
    transpose_to_bf16<<<dim3(4, 8),  b256, 0, stream>>>(g3W, wTg3, 256, 128, 128, 0, 0);
    transpose_to_bf16<<<dim3(4, 8),  b256, 0, stream>>>(r3W, wTr3, 256, 128, 128, 0, 0);

    // ---- Phase 1: MHA ----
    gemm_mfma<true, false, false, false, true><<<dim3(3, 200), b512, 0, stream>>>(
        x, wTq, bqkv, nullptr, qkvH, M, 400, 768, 400, 768, 0, 0, 0);
    mha_flash_mfma<<<dim3(7, 4, 64), b256, 0, stream>>>(qkvH, maskH, ctxH, 768);
    gemm_mfma<true, false, true, true, true><<<dim3(2, 200), b512, 0, stream>>>(
        ctxH, wTo, bo, x, xcH, M, 256, 400, 256, 400, 0, 0, 0);

    // ---- Phase 2: GAT1 (400 -> 256) ----
    gemm_mfma<true, false, false, true, false><<<dim3(2, 200), b512, 0, stream>>>(
        xcH, wTg1, bgr1, nullptr, hrF, M, 400, 512, 400, 512, 0, 0, 0);
    gat_srcdst<<<dim3(6400), b256, 0, stream>>>(hrF, g1a, srcb, dstb, 256, 512);
    gat_attn<<<dim3(6400), b256, 0, stream>>>(srcb, dstb, maskH, attn1, attnH);  // xc dead
    transpose_to_bf16<<<dim3(8, 13, 64), b256, 0, stream>>>(hrF, hT, 400, 256, 512, 204800, 102400);
    gemm_mfma<false, true, false, true, false><<<dim3(1, 4, 64), b512, 0, stream>>>(
        attnH, hT, nullptr, nullptr, hrF + 256, 400, 400, 256, 400, 512, 160000, 102400, 204800);
    ln_kernel<256, true, true><<<dim3(6400), b256, 0, stream>>>(hrF + 256, 512, ln1g, ln1b, x2H);

    // ---- Phase 3: GAT2 (256 -> 256) ----
    gemm_mfma<true, false, false, true, false><<<dim3(2, 200), b512, 0, stream>>>(
        x2H, wTg2, bgr2, nullptr, hrF, M, 256, 512, 256, 512, 0, 0, 0);
    gat_srcdst<<<dim3(6400), b256, 0, stream>>>(hrF, g2a, srcb, dstb, 256, 512);
    gat_attn<<<dim3(6400), b256, 0, stream>>>(srcb, dstb, maskH, attn2, attnH);
    transpose_to_bf16<<<dim3(8, 13, 64), b256, 0, stream>>>(hrF, hT, 400, 256, 512, 204800, 102400);
    gemm_mfma<false, true, false, true, false><<<dim3(1, 4, 64), b512, 0, stream>>>(
        attnH, hT, nullptr, nullptr, hrF + 256, 400, 400, 256, 400, 512, 160000, 102400, 204800);
    ln_kernel<256, true, true><<<dim3(6400), b256, 0, stream>>>(hrF + 256, 512, ln2g, ln2b, x2H);

    // ---- Phase 4: GAT3 (256 -> 128) ----
    gemm_mfma<true, false, false, true, false><<<dim3(1, 200), b512, 0, stream>>>(
        x2H, wTg3, bgr3, nullptr, hrF, M, 256, 256, 256, 256, 0, 0, 0);
    gat_srcdst<<<dim3(6400), b256, 0, stream>>>(hrF, g3a, srcb, dstb, 128, 256);
    gat_attn<<<dim3(6400), b256, 0, stream>>>(srcb, dstb, maskH, attn3, attnH);
    transpose_to_bf16<<<dim3(4, 13, 64), b256, 0, stream>>>(hrF, hT, 400, 128, 256, 102400, 51200);
    gemm_mfma<false, true, false, true, false><<<dim3(1, 4, 64), b512, 0, stream>>>(
        attnH, hT, nullptr, nullptr, hrF + 128, 400, 400, 128, 400, 256, 160000, 51200, 102400);
    ln_kernel<128, false, false><<<dim3(6400), b256, 0, stream>>>(hrF + 128, 256, ln3g, ln3b, out_x);
}

// Round 11
// 710.520 us; speedup vs baseline: 4.6806x; 1.0705x over previous
//
#include <hip/hip_runtime.h>

// GraphEncoder: MHA + 3×(GAT + residual-proj + LN[+ELU]).
// B=64, N=400, D=400, Hd=256, E=128, H=4, hd=64.
// bf16 dataflow; GAT tail (softmax+PV+res+LN) fused into one kernel/layer.
// d_out layout (f32): x_final [64*400*128] | attn1 [64*400*400] | attn2 | attn3

#define NEGBIG (-1e9f)

typedef __attribute__((ext_vector_type(8))) short bf16x8;
typedef __attribute__((ext_vector_type(4))) float f32x4;

__device__ inline unsigned short f2bf(float f) {
    unsigned u = __builtin_bit_cast(unsigned, f);
    u += 0x7fffu + ((u >> 16) & 1u);          // RNE
    return (unsigned short)(u >> 16);
}
__device__ inline float bf2f(unsigned short h) {
    unsigned u = ((unsigned)h) << 16;
    return __builtin_bit_cast(float, u);
}

__device__ inline float wave_sum(float v) {
#pragma unroll
    for (int off = 32; off >= 1; off >>= 1)
        v += __shfl_xor(v, off, 64);
    return v;
}
__device__ inline float wave_max(float v) {
#pragma unroll
    for (int off = 32; off >= 1; off >>= 1)
        v = fmaxf(v, __shfl_xor(v, off, 64));
    return v;
}

// ---------------------------------------------------------------------------
__global__ void build_biases(
    float* bqkv, const float* bq, const float* bk, const float* bv,
    float* bgr1, const float* r1b, float* bgr2, const float* r2b,
    float* bgr3, const float* r3b)
{
    const int t = threadIdx.x;
    bqkv[t] = bq[t]; bqkv[256 + t] = bk[t]; bqkv[512 + t] = bv[t];
    bgr1[t] = 0.f; bgr1[256 + t] = r1b[t];
    bgr2[t] = 0.f; bgr2[256 + t] = r2b[t];
    if (t < 128) { bgr3[t] = 0.f; bgr3[128 + t] = r3b[t]; }
}

// adj f32 -> additive maskbias bf16 (0 where edge, -1e9 where none)
__global__ __launch_bounds__(256) void adj2mask(
    const float* __restrict__ adj, unsigned short* __restrict__ mb)
{
    const long i = ((long)blockIdx.x * 256 + threadIdx.x) * 4;
    const float4 a = *reinterpret_cast<const float4*>(adj + i);
    ushort4 o;
    o.x = f2bf(a.x > 0.f ? 0.f : NEGBIG);
    o.y = f2bf(a.y > 0.f ? 0.f : NEGBIG);
    o.z = f2bf(a.z > 0.f ? 0.f : NEGBIG);
    o.w = f2bf(a.w > 0.f ? 0.f : NEGBIG);
    *reinterpret_cast<ushort4*>(mb + i) = o;
}

// ---------------------------------------------------------------------------
// Transpose + f32->bf16: out[c][r] = bf16(in[r][c]). (weights only)
__global__ __launch_bounds__(256) void transpose_to_bf16(
    const float* __restrict__ in, unsigned short* __restrict__ out,
    int R, int C, int ldIn)
{
    __shared__ float t[32][33];
    const int r0 = blockIdx.y * 32, c0 = blockIdx.x * 32;
    const int tid = threadIdx.x;

    const int row = tid >> 3, c4 = tid & 7;
    float4 v = make_float4(0.f, 0.f, 0.f, 0.f);
    if (r0 + row < R && c0 + c4 * 4 < C)
        v = *reinterpret_cast<const float4*>(&in[(long)(r0 + row) * ldIn + c0 + c4 * 4]);
    t[row][c4 * 4 + 0] = v.x;
    t[row][c4 * 4 + 1] = v.y;
    t[row][c4 * 4 + 2] = v.z;
    t[row][c4 * 4 + 3] = v.w;
    __syncthreads();

    const int oc = tid >> 3, r4 = tid & 7;
    if (c0 + oc < C && r0 + r4 * 4 < R) {
        ushort4 o;
        o.x = f2bf(t[r4 * 4 + 0][oc]);
        o.y = f2bf(t[r4 * 4 + 1][oc]);
        o.z = f2bf(t[r4 * 4 + 2][oc]);
        o.w = f2bf(t[r4 * 4 + 3][oc]);
        *reinterpret_cast<ushort4*>(&out[(long)(c0 + oc) * R + r0 + r4 * 4]) = o;
    }
}

// ---------------------------------------------------------------------------
// C[M,Nc] = A[M,K] @ BT[Nc,K](bf16)  (+bias)(+resid f32)
// A f32 (converted) or bf16 (ABHALF). C f32 or bf16 (OUTBF16).
// Tile 128x256x32, 512 threads = 8 waves (2x4), wave 64x64, mfma 16x16x32.
template<bool BIAS, bool RESID, bool ABHALF, bool OUTBF16>
__global__ __launch_bounds__(512) void gemm_mfma(
    const void* __restrict__ Av, const unsigned short* __restrict__ BT,
    const float* __restrict__ bias, const float* __restrict__ resid,
    void* __restrict__ Cv, int M, int K, int Nc, int ldA, int ldC)
{
    const float* Af = ABHALF ? nullptr : (const float*)Av;
    const unsigned short* Ah = ABHALF ? (const unsigned short*)Av : nullptr;
    float* Cf = OUTBF16 ? nullptr : (float*)Cv;
    unsigned short* Ch = OUTBF16 ? (unsigned short*)Cv : nullptr;

    __shared__ short As[128][40];
    __shared__ short Bs[256][40];

    const int tid = threadIdx.x;
    const int lane = tid & 63, wave = tid >> 6;
    const int wm = wave >> 2, wn = wave & 3;
    const int m0 = blockIdx.y * 128, n0 = blockIdx.x * 256;

    f32x4 acc[4][4] = {};

    const int nk = (K + 31) / 32;
    for (int kt = 0; kt < nk; ++kt) {
        const int k0 = kt * 32;
        __syncthreads();
        if (ABHALF) {
            const int row = tid >> 2, k8 = tid & 3;
            const int gm = m0 + row, gk = k0 + k8 * 8;
            uint4 av = make_uint4(0u, 0u, 0u, 0u);
            if (gm < M && gk < K)
                av = *reinterpret_cast<const uint4*>(&Ah[(long)gm * ldA + gk]);
            *reinterpret_cast<uint4*>(&As[row][k8 * 8]) = av;
        } else {
#pragma unroll
            for (int p = 0; p < 2; ++p) {
                const int idx = tid + p * 512;
                const int row = idx >> 3, k4 = idx & 7;
                const int gm = m0 + row, gk = k0 + k4 * 4;
                float4 av = make_float4(0.f, 0.f, 0.f, 0.f);
                if (gm < M && gk < K)
                    av = *reinterpret_cast<const float4*>(&Af[(long)gm * ldA + gk]);
                ushort4 h4;
                h4.x = f2bf(av.x); h4.y = f2bf(av.y); h4.z = f2bf(av.z); h4.w = f2bf(av.w);
                *reinterpret_cast<ushort4*>(&As[row][k4 * 4]) = h4;
            }
        }
#pragma unroll
        for (int p = 0; p < 2; ++p) {
            const int idx = tid + p * 512;
            const int n = idx >> 2, k8 = idx & 3;
            const int gn = n0 + n, gk = k0 + k8 * 8;
            uint4 bv = make_uint4(0u, 0u, 0u, 0u);
            if (gn < Nc && gk < K)
                bv = *reinterpret_cast<const uint4*>(&BT[(long)gn * K + gk]);
            *reinterpret_cast<uint4*>(&Bs[n][k8 * 8]) = bv;
        }
        __syncthreads();

        const int fr = lane & 15, fkb = (lane >> 4) * 8;
        bf16x8 a[4], b[4];
#pragma unroll
        for (int i = 0; i < 4; ++i)
            a[i] = *reinterpret_cast<const bf16x8*>(&As[wm * 64 + i * 16 + fr][fkb]);
#pragma unroll
        for (int j = 0; j < 4; ++j)
            b[j] = *reinterpret_cast<const bf16x8*>(&Bs[wn * 64 + j * 16 + fr][fkb]);
#pragma unroll
        for (int i = 0; i < 4; ++i)
#pragma unroll
            for (int j = 0; j < 4; ++j)
                acc[i][j] = __builtin_amdgcn_mfma_f32_16x16x32_bf16(a[i], b[j], acc[i][j], 0, 0, 0);
    }

    const int fr = lane & 15, rg = lane >> 4;
#pragma unroll
    for (int i = 0; i < 4; ++i) {
#pragma unroll
        for (int j = 0; j < 4; ++j) {
#pragma unroll
            for (int r = 0; r < 4; ++r) {
                const int gm = m0 + wm * 64 + i * 16 + rg * 4 + r;
                const int gn = n0 + wn * 64 + j * 16 + fr;
                if (gm < M && gn < Nc) {
                    float v = acc[i][j][r];
                    if (BIAS)  v += bias[gn];
                    if (RESID) v += resid[(long)gm * ldC + gn];
                    if (OUTBF16) Ch[(long)gm * ldC + gn] = f2bf(v);
                    else         Cf[(long)gm * ldC + gn] = v;
                }
            }
        }
    }
}

// ---------------------------------------------------------------------------
// Flash MHA on MFMA, bf16 in/out. qkv bf16 [25600][768]; mask bf16 additive.
__global__ __launch_bounds__(256) void mha_flash_mfma(
    const unsigned short* __restrict__ qkv, const unsigned short* __restrict__ mask,
    unsigned short* __restrict__ ctx, int ld)
{
    const int it = blockIdx.x, h = blockIdx.y, b = blockIdx.z;
    const int i0 = it * 64;
    const int tid = threadIdx.x;
    const int lane = tid & 63, w = tid >> 6;
    const int c = lane & 15, g = lane >> 4;
    const unsigned short NEGBF = f2bf(NEGBIG);

    __shared__ short Qs[64][72];
    __shared__ short Ks[64][72];
    __shared__ short Vt[64][72];
    __shared__ short Ps[64][72];
    __shared__ short Adjs[64][72];

    const long base_q = ((long)b * 400 + i0) * ld + h * 64;
#pragma unroll
    for (int p = 0; p < 2; ++p) {
        const int idx = tid + p * 256;
        const int r = idx >> 3, c8 = idx & 7;
        uint4 qv = make_uint4(0u, 0u, 0u, 0u);
        if (i0 + r < 400)
            qv = *reinterpret_cast<const uint4*>(qkv + base_q + (long)r * ld + c8 * 8);
        *reinterpret_cast<uint4*>(&Qs[r][c8 * 8]) = qv;
    }

    f32x4 o[4] = {};
    float m[4] = {-3e38f, -3e38f, -3e38f, -3e38f};
    float l[4] = {0.f, 0.f, 0.f, 0.f};

    for (int jt = 0; jt < 7; ++jt) {
        const int j0 = jt * 64;
        __syncthreads();

        const long base_k = ((long)b * 400 + j0) * ld + 256 + h * 64;
        const long base_v = base_k + 256;
#pragma unroll
        for (int p = 0; p < 2; ++p) {
            const int idx = tid + p * 256;
            const int r = idx >> 3, c8 = idx & 7;
            uint4 kv = make_uint4(0u, 0u, 0u, 0u);
            if (j0 + r < 400)
                kv = *reinterpret_cast<const uint4*>(qkv + base_k + (long)r * ld + c8 * 8);
            *reinterpret_cast<uint4*>(&Ks[r][c8 * 8]) = kv;

            ushort4 mb = make_ushort4(NEGBF, NEGBF, NEGBF, NEGBF);
            ushort4 mb2 = mb;
            if (i0 + r < 400 && j0 + c8 * 8 + 7 < 400) {
                const uint4 mv = *reinterpret_cast<const uint4*>(
                    mask + ((long)b * 400 + i0 + r) * 400 + j0 + c8 * 8);
                mb  = *reinterpret_cast<const ushort4*>(&mv.x);
                mb2 = *reinterpret_cast<const ushort4*>(&mv.z);
            }
            *reinterpret_cast<ushort4*>(&Adjs[r][c8 * 8]) = mb;
            *reinterpret_cast<ushort4*>(&Adjs[r][c8 * 8 + 4]) = mb2;
        }
        {
            const int j4 = tid >> 4, d4 = tid & 15;
            ushort4 vl[4];
#pragma unroll
            for (int t = 0; t < 4; ++t) {
                vl[t] = make_ushort4(0, 0, 0, 0);
                if (j0 + j4 * 4 + t < 400)
                    vl[t] = *reinterpret_cast<const ushort4*>(qkv + base_v + (long)(j4 * 4 + t) * ld + d4 * 4);
            }
#pragma unroll
            for (int u = 0; u < 4; ++u) {
                ushort4 h4;
                h4.x = ((const unsigned short*)&vl[0])[u];
                h4.y = ((const unsigned short*)&vl[1])[u];
                h4.z = ((const unsigned short*)&vl[2])[u];
                h4.w = ((const unsigned short*)&vl[3])[u];
                *reinterpret_cast<ushort4*>(&Vt[d4 * 4 + u][j4 * 4]) = h4;
            }
        }
        __syncthreads();

        f32x4 s4[4] = {};
#pragma unroll
        for (int ks = 0; ks < 2; ++ks) {
            const bf16x8 a = *reinterpret_cast<const bf16x8*>(&Qs[w * 16 + c][ks * 32 + g * 8]);
#pragma unroll
            for (int t = 0; t < 4; ++t) {
                const bf16x8 bb = *reinterpret_cast<const bf16x8*>(&Ks[t * 16 + c][ks * 32 + g * 8]);
                s4[t] = __builtin_amdgcn_mfma_f32_16x16x32_bf16(a, bb, s4[t], 0, 0, 0);
            }
        }

        float e[4][4];
        float pmax[4];
#pragma unroll
        for (int reg = 0; reg < 4; ++reg) {
            const int qr = w * 16 + g * 4 + reg;
            float mx = -3e38f;
#pragma unroll
            for (int t = 0; t < 4; ++t) {
                const float ev = s4[t][reg] * 0.125f + bf2f((unsigned short)Adjs[qr][t * 16 + c]);
                e[t][reg] = ev;
                mx = fmaxf(mx, ev);
            }
            pmax[reg] = mx;
        }
#pragma unroll
        for (int reg = 0; reg < 4; ++reg)
#pragma unroll
            for (int off = 1; off <= 8; off <<= 1)
                pmax[reg] = fmaxf(pmax[reg], __shfl_xor(pmax[reg], off, 64));

        float al[4];
#pragma unroll
        for (int reg = 0; reg < 4; ++reg) {
            const float mn = fmaxf(m[reg], pmax[reg]);
            al[reg] = __expf(m[reg] - mn);
            m[reg] = mn;
        }

#pragma unroll
        for (int reg = 0; reg < 4; ++reg) {
            const int qr = w * 16 + g * 4 + reg;
            float psum = 0.f;
#pragma unroll
            for (int t = 0; t < 4; ++t) {
                const float p = __expf(e[t][reg] - m[reg]);
                psum += p;
                Ps[qr][t * 16 + c] = (short)f2bf(p);
            }
            l[reg] = l[reg] * al[reg] + psum;
        }

#pragma unroll
        for (int dt = 0; dt < 4; ++dt)
#pragma unroll
            for (int reg = 0; reg < 4; ++reg)
                o[dt][reg] *= al[reg];

#pragma unroll
        for (int ks = 0; ks < 2; ++ks) {
            const bf16x8 a = *reinterpret_cast<const bf16x8*>(&Ps[w * 16 + c][ks * 32 + g * 8]);
#pragma unroll
            for (int dt = 0; dt < 4; ++dt) {
                const bf16x8 bb = *reinterpret_cast<const bf16x8*>(&Vt[dt * 16 + c][ks * 32 + g * 8]);
                o[dt] = __builtin_amdgcn_mfma_f32_16x16x32_bf16(a, bb, o[dt], 0, 0, 0);
            }
        }
    }

#pragma unroll
    for (int reg = 0; reg < 4; ++reg)
#pragma unroll
        for (int off = 1; off <= 8; off <<= 1)
            l[reg] += __shfl_xor(l[reg], off, 64);

#pragma unroll
    for (int reg = 0; reg < 4; ++reg) {
        const int gi = i0 + w * 16 + g * 4 + reg;
        if (gi < 400) {
            const float inv = 1.f / l[reg];
#pragma unroll
            for (int dt = 0; dt < 4; ++dt)
                ctx[((long)b * 400 + gi) * 256 + h * 64 + dt * 16 + c] = f2bf(o[dt][reg] * inv);
        }
    }
}

// src/dst projections from bf16 h (row stride 2F).
template<int F>
__global__ __launch_bounds__(256) void gat_srcdst_h(
    const unsigned short* __restrict__ h, const float* __restrict__ a,
    float* __restrict__ src, float* __restrict__ dst)
{
    const int row = blockIdx.x * 4 + (threadIdx.x >> 6);
    const int lane = threadIdx.x & 63;
    constexpr int PER = F / 64;
    const unsigned short* hp = h + (long)row * (2 * F) + lane * PER;
    float s = 0.f, d = 0.f;
#pragma unroll
    for (int u = 0; u < PER; ++u) {
        const float hv = bf2f(hp[u]);
        s += hv * a[lane * PER + u];
        d += hv * a[F + lane * PER + u];
    }
    s = wave_sum(s);
    d = wave_sum(d);
    if (lane == 0) { src[row] = s; dst[row] = d; }
}

// ---------------------------------------------------------------------------
// Fused GAT tail: row-softmax (attn out f32) + PV (MFMA) + residual + LN(+ELU).
// Grid (7 i-tiles, 64 batches), 256 threads = 4 waves; wave w owns rows w*16..+15.
// hr bf16 [B*400][2F]: h cols 0..F-1, res cols F..2F-1.
template<int F, bool ELU, bool OUTB16>
__global__ __launch_bounds__(256) void gat_fused(
    const float* __restrict__ src, const float* __restrict__ dst,
    const unsigned short* __restrict__ mask,
    const unsigned short* __restrict__ hr,
    const float* __restrict__ gam, const float* __restrict__ bet,
    float* __restrict__ attn, void* __restrict__ xout)
{
    constexpr int LD = 2 * F;
    constexpr int DT = F / 16;       // col tiles
    constexpr int DG = F / 4;        // d-groups per k-step staging
    constexpr int NP = (8 * DG) / 256;

    const int it = blockIdx.x, b = blockIdx.y;
    const int i0 = it * 64;
    const int tid = threadIdx.x;
    const int lane = tid & 63, w = tid >> 6;
    const int c = lane & 15, g = lane >> 4;

    __shared__ short Ps[64][424];    // P bf16, wave-private row bands (pad->2-way banks)
    __shared__ short Ht[F][40];      // h^T tile for current k-step

    // ---- softmax phase: wave w handles rows w*16 .. w*16+15 serially
    const float* drow = dst + (long)b * 400;
    for (int rr = 0; rr < 16; ++rr) {
        const int r = w * 16 + rr;
        const int gi = i0 + r;
        const int giq = gi < 400 ? gi : 399;        // clamp (garbage rows unused)
        const float si = src[(long)b * 400 + giq];
        const unsigned short* mrow = mask + ((long)b * 400 + giq) * 400;
        float e[7];
        float mx = -3e38f;
#pragma unroll
        for (int t = 0; t < 7; ++t) {
            const int j = lane + 64 * t;
            float v = -3e38f;
            if (j < 400) {
                v = si + drow[j];
                v = (v > 0.f) ? v : 0.2f * v;
                v += bf2f(mrow[j]);
            }
            e[t] = v;
            mx = fmaxf(mx, v);
        }
        mx = wave_max(mx);
        float p[7], sum = 0.f;
#pragma unroll
        for (int t = 0; t < 7; ++t) {
            const int j = lane + 64 * t;
            if (j < 400) { p[t] = __expf(e[t] - mx); sum += p[t]; }
        }
        sum = wave_sum(sum);
        const float inv = 1.f / sum;
#pragma unroll
        for (int t = 0; t < 7; ++t) {
            const int j = lane + 64 * t;
            if (j < 400) {
                const float pv = p[t] * inv;
                if (gi < 400) attn[((long)b * 400 + gi) * 400 + j] = pv;
                Ps[r][j] = (short)f2bf(pv);
            } else if (j < 416) {
                Ps[r][j] = 0;                       // zero K-pad (k loop reads to 415)
            }
        }
    }

    // ---- PV phase: O = P @ h, K=400 in 13 steps of 32
    f32x4 acc[DT] = {};
    const long hbase = (long)b * 400 * LD;
    for (int kt = 0; kt < 13; ++kt) {
        const int k0 = kt * 32;
        __syncthreads();                            // prev Ht reads done / softmax done
#pragma unroll
        for (int p = 0; p < NP; ++p) {
            const int slot = tid + p * 256;
            const int kg = slot / DG, dg = slot % DG;
            ushort4 vl[4];
#pragma unroll
            for (int t = 0; t < 4; ++t) {
                const int j = k0 + kg * 4 + t;
                vl[t] = make_ushort4(0, 0, 0, 0);
                if (j < 400)
                    vl[t] = *reinterpret_cast<const ushort4*>(&hr[hbase + (long)j * LD + dg * 4]);
            }
#pragma unroll
            for (int u = 0; u < 4; ++u) {
                ushort4 h4;
                h4.x = ((const unsigned short*)&vl[0])[u];
                h4.y = ((const unsigned short*)&vl[1])[u];
                h4.z = ((const unsigned short*)&vl[2])[u];
                h4.w = ((const unsigned short*)&vl[3])[u];
                *reinterpret_cast<ushort4*>(&Ht[dg * 4 + u][kg * 4]) = h4;
            }
        }
        __syncthreads();

        const bf16x8 a = *reinterpret_cast<const bf16x8*>(&Ps[w * 16 + c][k0 + g * 8]);
#pragma unroll
        for (int dt = 0; dt < DT; ++dt) {
            const bf16x8 bb = *reinterpret_cast<const bf16x8*>(&Ht[dt * 16 + c][g * 8]);
            acc[dt] = __builtin_amdgcn_mfma_f32_16x16x32_bf16(a, bb, acc[dt], 0, 0, 0);
        }
    }

    // ---- epilogue: + res, LayerNorm(+ELU), store
#pragma unroll
    for (int reg = 0; reg < 4; ++reg) {
        const int row = w * 16 + g * 4 + reg;
        const int gi = i0 + row;
        const int giq = gi < 400 ? gi : 399;
        const long rb = hbase + (long)giq * LD + F;
        float v[DT];
        float s = 0.f;
#pragma unroll
        for (int dt = 0; dt < DT; ++dt) {
            v[dt] = acc[dt][reg] + bf2f(hr[rb + dt * 16 + c]);
            s += v[dt];
        }
#pragma unroll
        for (int off = 1; off <= 8; off <<= 1) s += __shfl_xor(s, off, 64);
        const float mean = s * (1.f / F);
        float vs = 0.f;
#pragma unroll
        for (int dt = 0; dt < DT; ++dt) {
            const float d = v[dt] - mean;
            vs += d * d;
        }
#pragma unroll
        for (int off = 1; off <= 8; off <<= 1) vs += __shfl_xor(vs, off, 64);
        const float rstd = rsqrtf(vs * (1.f / F) + 1e-5f);
        if (gi < 400) {
#pragma unroll
            for (int dt = 0; dt < DT; ++dt) {
                const int col = dt * 16 + c;
                float y = (v[dt] - mean) * rstd * gam[col] + bet[col];
                if (ELU) y = (y > 0.f) ? y : expm1f(y);
                if (OUTB16)
                    ((unsigned short*)xout)[((long)b * 400 + gi) * F + col] = f2bf(y);
                else
                    ((float*)xout)[((long)b * 400 + gi) * F + col] = y;
            }
        }
    }
}

extern "C" void kernel_launch(void* const* d_in, const int* in_sizes, int n_in,
                              void* d_out, int out_size, void* d_ws, size_t ws_size,
                              hipStream_t stream) {
    const float* x    = (const float*)d_in[0];
    const float* adj  = (const float*)d_in[1];
    const float* Wq   = (const float*)d_in[2];
    const float* bq   = (const float*)d_in[3];
    const float* Wk   = (const float*)d_in[4];
    const float* bk   = (const float*)d_in[5];
    const float* Wv   = (const float*)d_in[6];
    const float* bv   = (const float*)d_in[7];
    const float* Wo   = (const float*)d_in[8];
    const float* bo   = (const float*)d_in[9];
    const float* g1W  = (const float*)d_in[10];
    const float* g1a  = (const float*)d_in[11];
    const float* g2W  = (const float*)d_in[12];
    const float* g2a  = (const float*)d_in[13];
    const float* g3W  = (const float*)d_in[14];
    const float* g3a  = (const float*)d_in[15];
    const float* r1W  = (const float*)d_in[16];
    const float* r1b  = (const float*)d_in[17];
    const float* r2W  = (const float*)d_in[18];
    const float* r2b  = (const float*)d_in[19];
    const float* r3W  = (const float*)d_in[20];
    const float* r3b  = (const float*)d_in[21];
    const float* ln1g = (const float*)d_in[22];
    const float* ln1b = (const float*)d_in[23];
    const float* ln2g = (const float*)d_in[24];
    const float* ln2b = (const float*)d_in[25];
    const float* ln3g = (const float*)d_in[26];
    const float* ln3b = (const float*)d_in[27];

    float* out_x = (float*)d_out;              // [25600,128]
    float* attn1 = out_x + 3276800;            // [64,400,400]
    float* attn2 = attn1 + 10240000;
    float* attn3 = attn2 + 10240000;

    char* wsb = (char*)d_ws;
    // R1 [0, 52.4MB): hrH bf16 [25600][512]; early alias: ctx bf16 [25600][256]
    unsigned short* hrH  = (unsigned short*)wsb;
    unsigned short* ctxH = (unsigned short*)wsb;
    // R2 [52.4, 91.8MB): qkv bf16 [25600][768]; later x2H bf16 [25600][256]
    unsigned short* qkvH = (unsigned short*)(wsb + 52428800);
    unsigned short* x2H  = qkvH;
    // R3 [91.8, 112.2MB): maskbias bf16 [64][400][400]
    unsigned short* maskH = (unsigned short*)(wsb + 91750400);
    // R4: small
    float* srcb = (float*)(wsb + 112230400);   // [25600]
    float* dstb = (float*)(wsb + 112332800);   // [25600]
    unsigned short* wT = (unsigned short*)(wsb + 112435200);
    unsigned short* wTq  = wT;                 // [256][400]
    unsigned short* wTk  = wT + 102400;
    unsigned short* wTv  = wT + 204800;
    unsigned short* wTo  = wT + 307200;        // [400][256]
    unsigned short* wTg1 = wT + 409600;        // [256][400]
    unsigned short* wTr1 = wT + 512000;
    unsigned short* wTg2 = wT + 614400;        // [256][256]
    unsigned short* wTr2 = wT + 679936;
    unsigned short* wTg3 = wT + 745472;        // [128][256]
    unsigned short* wTr3 = wT + 778240;
    float* bqkv = (float*)(wsb + 114057216);   // [768]
    float* bgr1 = bqkv + 768;                  // [512]
    float* bgr2 = bgr1 + 512;                  // [512]
    float* bgr3 = bgr2 + 512;                  // [256]
    unsigned short* xcH = (unsigned short*)attn1;   // xc bf16 in attn1 region (dead before gat_fused1)

    const dim3 b256(256), b512(512);
    const int M = 25600;

    // ---- Phase 0 ----
    build_biases<<<1, b256, 0, stream>>>(bqkv, bq, bk, bv, bgr1, r1b, bgr2, r2b, bgr3, r3b);
    adj2mask<<<dim3(10000), b256, 0, stream>>>(adj, maskH);
    transpose_to_bf16<<<dim3(8, 13), b256, 0, stream>>>(Wq,  wTq, 400, 256, 256);
    transpose_to_bf16<<<dim3(8, 13), b256, 0, stream>>>(Wk,  wTk, 400, 256, 256);
    transpose_to_bf16<<<dim3(8, 13), b256, 0, stream>>>(Wv,  wTv, 400, 256, 256);
    transpose_to_bf16<<<dim3(13, 8), b256, 0, stream>>>(Wo,  wTo, 256, 400, 400);
    transpose_to_bf16<<<dim3(8, 13), b256, 0, stream>>>(g1W, wTg1, 400, 256, 256);
    transpose_to_bf16<<<dim3(8, 13), b256, 0, stream>>>(r1W, wTr1, 400, 256, 256);
    transpose_to_bf16<<<dim3(8, 8),  b256, 0, stream>>>(g2W, wTg2, 256, 256, 256);
    transpose_to_bf16<<<dim3(8, 8),  b256, 0, stream>>>(r2W, wTr2, 256, 256, 256);
    transpose_to_bf16<<<dim3(4, 8),  b256, 0, stream>>>(g3W, wTg3, 256, 128, 128);
    transpose_to_bf16<<<dim3(4, 8),  b256, 0, stream>>>(r3W, wTr3, 256, 128, 128);

    // ---- Phase 1: MHA ----
    gemm_mfma<true, false, false, true><<<dim3(3, 200), b512, 0, stream>>>(
        x, wTq, bqkv, nullptr, qkvH, M, 400, 768, 400, 768);
    mha_flash_mfma<<<dim3(7, 4, 64), b256, 0, stream>>>(qkvH, maskH, ctxH, 768);
    gemm_mfma<true, true, true, true><<<dim3(2, 200), b512, 0, stream>>>(
        ctxH, wTo, bo, x, xcH, M, 256, 400, 256, 400);

    // ---- Phase 2: GAT1 (400 -> 256) ----
    gemm_mfma<true, false, true, true><<<dim3(2, 200), b512, 0, stream>>>(
        xcH, wTg1, bgr1, nullptr, hrH, M, 400, 512, 400, 512);
    gat_srcdst_h<256><<<dim3(6400), b256, 0, stream>>>(hrH, g1a, srcb, dstb);
    gat_fused<256, true, true><<<dim3(7, 64), b256, 0, stream>>>(
        srcb, dstb, maskH, hrH, ln1g, ln1b, attn1, x2H);   // xc dead from here

    // ---- Phase 3: GAT2 (256 -> 256) ----
    gemm_mfma<true, false, true, true><<<dim3(2, 200), b512, 0, stream>>>(
        x2H, wTg2, bgr2, nullptr, hrH, M, 256, 512, 256, 512);
    gat_srcdst_h<256><<<dim3(6400), b256, 0, stream>>>(hrH, g2a, srcb, dstb);
    gat_fused<256, true, true><<<dim3(7, 64), b256, 0, stream>>>(
        srcb, dstb, maskH, hrH, ln2g, ln2b, attn2, x2H);

    // ---- Phase 4: GAT3 (256 -> 128) ----
    gemm_mfma<true, false, true, true><<<dim3(1, 200), b512, 0, stream>>>(
        x2H, wTg3, bgr3, nullptr, hrH, M, 256, 256, 256, 256);
    gat_srcdst_h<128><<<dim3(6400), b256, 0, stream>>>(hrH, g3a, srcb, dstb);
    gat_fused<128, false, false><<<dim3(7, 64), b256, 0, stream>>>(
        srcb, dstb, maskH, hrH, ln3g, ln3b, attn3, out_x);
}